// Round 4
// baseline (926.805 us; speedup 1.0000x reference)
//
#include <hip/hip_runtime.h>
#include <math.h>

#define BB 2
#define VV 8
#define NQ 336
#define DD 256
#define HEADS 8
#define HD 32
#define FF 1024
#define NL 6
#define BQ (BB*NQ)
#define W_IMG 512
#define H_IMG 512
#define MROWS BQ

// ================= job: 128ch x 32px transpose tile (5376 tiles) =================
// 16.9 KB LDS -> 8 blocks/CU (wave-capped). 512B-contiguous channel writes.
// At 7.7 TB/s combined fabric throughput (r3 counters) — memory-system-limited.
__device__ __forceinline__ void job_transpose3(float* tile, int b,
                                               const float* __restrict__ f0,
                                               const float* __restrict__ f1,
                                               const float* __restrict__ f2,
                                               float* __restrict__ o0,
                                               float* __restrict__ o1,
                                               float* __restrict__ o2) {
    const float* src; float* dst; int HW, ptiles;
    if (b < 4096)      { src = f0; dst = o0; HW = 4096; ptiles = 128; }
    else if (b < 5120) { b -= 4096; src = f1; dst = o1; HW = 1024; ptiles = 32; }
    else               { b -= 5120; src = f2; dst = o2; HW = 256;  ptiles = 8;  }
    int cg = b & 1;
    int pt = (b >> 1) % ptiles;
    int bv = (b >> 1) / ptiles;
    int d0 = cg * 128, p0 = pt * 32;
    int t = threadIdx.x;
    int chb = t >> 3, px4 = (t & 7) * 4;
    #pragma unroll
    for (int pass = 0; pass < 4; ++pass) {
        int ch = pass * 32 + chb;
        float4 v = *(const float4*)(src + ((size_t)(bv * DD + d0 + ch)) * HW + p0 + px4);
        tile[ch * 33 + px4 + 0] = v.x; tile[ch * 33 + px4 + 1] = v.y;
        tile[ch * 33 + px4 + 2] = v.z; tile[ch * 33 + px4 + 3] = v.w;
    }
    __syncthreads();
    int c4 = (t & 31) * 4, pxb = t >> 5;
    #pragma unroll
    for (int pass = 0; pass < 4; ++pass) {
        int px = pass * 8 + pxb;
        float4 o;
        o.x = tile[(c4 + 0) * 33 + px];
        o.y = tile[(c4 + 1) * 33 + px];
        o.z = tile[(c4 + 2) * 33 + px];
        o.w = tile[(c4 + 3) * 33 + px];
        *(float4*)(dst + ((size_t)bv * HW + p0 + px) * DD + d0 + c4) = o;
    }
}

// ================= init (168 blocks) =================
__global__ __launch_bounds__(256) void init_k(const float* __restrict__ tgt,
                                              const float* __restrict__ qp,
                                              const float* __restrict__ refpts,
                                              float* __restrict__ x,
                                              float* __restrict__ xq,
                                              float* __restrict__ refb) {
    int i = blockIdx.x * 256 + threadIdx.x;
    float4 tv = ((const float4*)tgt)[i];
    float4 qv = ((const float4*)qp)[i];
    ((float4*)x)[i] = tv;
    ((float4*)xq)[i] = make_float4(tv.x + qv.x, tv.y + qv.y, tv.z + qv.z, tv.w + qv.w);
    if (i < BQ * 3) refb[i] = refpts[i];
}

// ================= job: 32x64 qkv tile, head-packed output =================
__device__ __forceinline__ void job_qkv(float* sm, int bid,
                                        const float* __restrict__ Aq,
                                        const float* __restrict__ Ax,
                                        const float* __restrict__ W,
                                        const float* __restrict__ bias,
                                        float* __restrict__ Qp,
                                        float* __restrict__ Kp,
                                        float* __restrict__ Vp) {
    float* At = sm;            // [32][34]
    float* Wt = sm + 1088;     // [32][68]
    int t = threadIdx.x;
    int m0 = (bid % 21) * 32;
    int ncol = bid / 21;
    int n0 = ncol * 64;
    const float* A = (ncol < 8) ? Aq : Ax;
    int tx = t & 15, ty = t >> 4;
    int nc = n0 + tx * 4;
    float acc0[4], acc1[4];
    {
        float4 bv = *(const float4*)(bias + nc);
        acc0[0] = bv.x; acc0[1] = bv.y; acc0[2] = bv.z; acc0[3] = bv.w;
        acc1[0] = bv.x; acc1[1] = bv.y; acc1[2] = bv.z; acc1[3] = bv.w;
    }
    int am = t >> 3, ak4 = (t & 7) * 4;
    for (int kt = 0; kt < 8; ++kt) {
        int kk = kt * 32;
        __syncthreads();
        {
            float4 v = *(const float4*)(A + (size_t)(m0 + am) * DD + kk + ak4);
            At[(ak4 + 0) * 34 + am] = v.x; At[(ak4 + 1) * 34 + am] = v.y;
            At[(ak4 + 2) * 34 + am] = v.z; At[(ak4 + 3) * 34 + am] = v.w;
        }
        #pragma unroll
        for (int s = 0; s < 2; ++s) {
            int idx = t + s * 256;
            int wn = idx >> 3, wk4 = (idx & 7) * 4;
            float4 v = *(const float4*)(W + (size_t)(n0 + wn) * DD + kk + wk4);
            Wt[(wk4 + 0) * 68 + wn] = v.x; Wt[(wk4 + 1) * 68 + wn] = v.y;
            Wt[(wk4 + 2) * 68 + wn] = v.z; Wt[(wk4 + 3) * 68 + wn] = v.w;
        }
        __syncthreads();
        #pragma unroll
        for (int k = 0; k < 32; ++k) {
            float2 av = *(const float2*)&At[k * 34 + ty * 2];
            float4 wv = *(const float4*)&Wt[k * 68 + tx * 4];
            acc0[0] = fmaf(av.x, wv.x, acc0[0]); acc0[1] = fmaf(av.x, wv.y, acc0[1]);
            acc0[2] = fmaf(av.x, wv.z, acc0[2]); acc0[3] = fmaf(av.x, wv.w, acc0[3]);
            acc1[0] = fmaf(av.y, wv.x, acc1[0]); acc1[1] = fmaf(av.y, wv.y, acc1[1]);
            acc1[2] = fmaf(av.y, wv.z, acc1[2]); acc1[3] = fmaf(av.y, wv.w, acc1[3]);
        }
    }
    int mr = m0 + ty * 2;
    int kind = nc >> 8;
    float* base = kind == 0 ? Qp : (kind == 1 ? Kp : Vp);
    int h = (nc >> 5) & 7, d4 = nc & 31;
    #pragma unroll
    for (int i = 0; i < 2; ++i) {
        int m = mr + i;
        int b = m / NQ, q = m - b * NQ;
        float* p = base + ((size_t)((b << 3) + h) * NQ + q) * HD + d4;
        float* src = i == 0 ? acc0 : acc1;
        *(float4*)p = make_float4(src[0], src[1], src[2], src[3]);
    }
}

// ================= job: pose MLP + heads for 4 rows =================
__device__ __forceinline__ void job_pose(float* sm, int job,
                                         const float* __restrict__ x,
                                         const float* __restrict__ W0, const float* __restrict__ b0,
                                         const float* __restrict__ W1p, const float* __restrict__ b1p,
                                         const float* __restrict__ W2p, const float* __restrict__ b2p,
                                         const float* __restrict__ cW, const float* __restrict__ cb,
                                         float* __restrict__ refb, float* __restrict__ outp) {
    float* sX  = sm;          // 1024
    float* sH  = sm + 1024;   // 1024
    float* red = sm + 2048;   // 64
    int r0 = job * 4;
    int tid = threadIdx.x;
    ((float4*)sX)[tid] = ((const float4*)(x + (size_t)r0 * DD))[tid];
    __syncthreads();
    {
        float a0 = b0[tid], a1 = a0, a2 = a0, a3 = a0;
        const float* wp = W0 + (size_t)tid * DD;
        for (int k = 0; k < DD; k += 4) {
            float4 w  = *(const float4*)(wp + k);
            float4 x0 = *(const float4*)(sX + 0 * DD + k);
            float4 x1 = *(const float4*)(sX + 1 * DD + k);
            float4 x2 = *(const float4*)(sX + 2 * DD + k);
            float4 x3 = *(const float4*)(sX + 3 * DD + k);
            a0 = fmaf(x0.x, w.x, a0); a0 = fmaf(x0.y, w.y, a0); a0 = fmaf(x0.z, w.z, a0); a0 = fmaf(x0.w, w.w, a0);
            a1 = fmaf(x1.x, w.x, a1); a1 = fmaf(x1.y, w.y, a1); a1 = fmaf(x1.z, w.z, a1); a1 = fmaf(x1.w, w.w, a1);
            a2 = fmaf(x2.x, w.x, a2); a2 = fmaf(x2.y, w.y, a2); a2 = fmaf(x2.z, w.z, a2); a2 = fmaf(x2.w, w.w, a2);
            a3 = fmaf(x3.x, w.x, a3); a3 = fmaf(x3.y, w.y, a3); a3 = fmaf(x3.z, w.z, a3); a3 = fmaf(x3.w, w.w, a3);
        }
        sH[0 * DD + tid] = fmaxf(a0, 0.f);
        sH[1 * DD + tid] = fmaxf(a1, 0.f);
        sH[2 * DD + tid] = fmaxf(a2, 0.f);
        sH[3 * DD + tid] = fmaxf(a3, 0.f);
    }
    __syncthreads();
    float h[4];
    {
        float a0 = b1p[tid], a1 = a0, a2 = a0, a3 = a0;
        const float* wp = W1p + (size_t)tid * DD;
        for (int k = 0; k < DD; k += 4) {
            float4 w  = *(const float4*)(wp + k);
            float4 x0 = *(const float4*)(sH + 0 * DD + k);
            float4 x1 = *(const float4*)(sH + 1 * DD + k);
            float4 x2 = *(const float4*)(sH + 2 * DD + k);
            float4 x3 = *(const float4*)(sH + 3 * DD + k);
            a0 = fmaf(x0.x, w.x, a0); a0 = fmaf(x0.y, w.y, a0); a0 = fmaf(x0.z, w.z, a0); a0 = fmaf(x0.w, w.w, a0);
            a1 = fmaf(x1.x, w.x, a1); a1 = fmaf(x1.y, w.y, a1); a1 = fmaf(x1.z, w.z, a1); a1 = fmaf(x1.w, w.w, a1);
            a2 = fmaf(x2.x, w.x, a2); a2 = fmaf(x2.y, w.y, a2); a2 = fmaf(x2.z, w.z, a2); a2 = fmaf(x2.w, w.w, a2);
            a3 = fmaf(x3.x, w.x, a3); a3 = fmaf(x3.y, w.y, a3); a3 = fmaf(x3.z, w.z, a3); a3 = fmaf(x3.w, w.w, a3);
        }
        h[0] = fmaxf(a0, 0.f); h[1] = fmaxf(a1, 0.f); h[2] = fmaxf(a2, 0.f); h[3] = fmaxf(a3, 0.f);
    }
    float w2a = W2p[tid], w2b = W2p[DD + tid], w2c = W2p[2 * DD + tid], cw = cW[tid];
    float v[4][4];
    #pragma unroll
    for (int r = 0; r < 4; ++r) {
        v[r][0] = h[r] * w2a;
        v[r][1] = h[r] * w2b;
        v[r][2] = h[r] * w2c;
        v[r][3] = sX[r * DD + tid] * cw;
    }
    #pragma unroll
    for (int o2 = 32; o2 > 0; o2 >>= 1) {
        #pragma unroll
        for (int r = 0; r < 4; ++r) {
            #pragma unroll
            for (int c = 0; c < 4; ++c) v[r][c] += __shfl_xor(v[r][c], o2);
        }
    }
    int wid = tid >> 6, lane = tid & 63;
    if (lane == 0) {
        #pragma unroll
        for (int r = 0; r < 4; ++r) {
            #pragma unroll
            for (int c = 0; c < 4; ++c) red[(r * 4 + c) * 4 + wid] = v[r][c];
        }
    }
    __syncthreads();
    if (tid < 4) {
        int r = tid;
        float d0 = red[(r * 4 + 0) * 4 + 0] + red[(r * 4 + 0) * 4 + 1] + red[(r * 4 + 0) * 4 + 2] + red[(r * 4 + 0) * 4 + 3] + b2p[0];
        float d1 = red[(r * 4 + 1) * 4 + 0] + red[(r * 4 + 1) * 4 + 1] + red[(r * 4 + 1) * 4 + 2] + red[(r * 4 + 1) * 4 + 3] + b2p[1];
        float d2 = red[(r * 4 + 2) * 4 + 0] + red[(r * 4 + 2) * 4 + 1] + red[(r * 4 + 2) * 4 + 2] + red[(r * 4 + 2) * 4 + 3] + b2p[2];
        float cl = red[(r * 4 + 3) * 4 + 0] + red[(r * 4 + 3) * 4 + 1] + red[(r * 4 + 3) * 4 + 2] + red[(r * 4 + 3) * 4 + 3] + cb[0];
        int row = r0 + r;
        float rx = refb[(size_t)row * 3 + 0] + d0;
        float ry = refb[(size_t)row * 3 + 1] + d1;
        float rz = refb[(size_t)row * 3 + 2] + d2;
        refb[(size_t)row * 3 + 0] = rx;
        refb[(size_t)row * 3 + 1] = ry;
        refb[(size_t)row * 3 + 2] = rz;
        outp[(size_t)row * 4 + 0] = cl;
        outp[(size_t)row * 4 + 1] = rx;
        outp[(size_t)row * 4 + 2] = ry;
        outp[(size_t)row * 4 + 3] = rz;
    }
}

// ================= fused dispatch A: qkv (252) + pose of prev layer (168) =================
__global__ __launch_bounds__(256) void qkv_pose(const float* __restrict__ xq,
                                                const float* __restrict__ x,
                                                const float* __restrict__ Wqkv,
                                                const float* __restrict__ bqkv,
                                                float* __restrict__ Qp,
                                                float* __restrict__ Kp,
                                                float* __restrict__ Vp,
                                                const float* __restrict__ pW0, const float* __restrict__ pb0,
                                                const float* __restrict__ pW1, const float* __restrict__ pb1,
                                                const float* __restrict__ pW2, const float* __restrict__ pb2,
                                                const float* __restrict__ cW, const float* __restrict__ cb,
                                                float* __restrict__ refb, float* __restrict__ outp) {
    __shared__ float sm[3264];
    if (blockIdx.x < 252)
        job_qkv(sm, blockIdx.x, xq, x, Wqkv, bqkv, Qp, Kp, Vp);
    else
        job_pose(sm, blockIdx.x - 252, x, pW0, pb0, pW1, pb1, pW2, pb2, cW, cb, refb, outp);
}

// ================= layer-0 variant: qkv (252) + full transpose (5376) =================
__global__ __launch_bounds__(256) void qkv_tr(const float* __restrict__ xq,
                                              const float* __restrict__ x,
                                              const float* __restrict__ Wqkv,
                                              const float* __restrict__ bqkv,
                                              float* __restrict__ Qp,
                                              float* __restrict__ Kp,
                                              float* __restrict__ Vp,
                                              const float* __restrict__ f0,
                                              const float* __restrict__ f1,
                                              const float* __restrict__ f2,
                                              float* __restrict__ o0,
                                              float* __restrict__ o1,
                                              float* __restrict__ o2) {
    __shared__ float sm[4224];
    if (blockIdx.x < 252)
        job_qkv(sm, blockIdx.x, xq, x, Wqkv, bqkv, Qp, Kp, Vp);
    else
        job_transpose3(sm, blockIdx.x - 252, f0, f1, f2, o0, o1, o2);
}

// standalone pose (tail)
__global__ __launch_bounds__(256) void pose_only(const float* __restrict__ x,
                                                 const float* __restrict__ pW0, const float* __restrict__ pb0,
                                                 const float* __restrict__ pW1, const float* __restrict__ pb1,
                                                 const float* __restrict__ pW2, const float* __restrict__ pb2,
                                                 const float* __restrict__ cW, const float* __restrict__ cb,
                                                 float* __restrict__ refb, float* __restrict__ outp) {
    __shared__ float sm[2112];
    job_pose(sm, blockIdx.x, x, pW0, pb0, pW1, pb1, pW2, pb2, cW, cb, refb, outp);
}

// ================= job: 16-row fused attention tile (scores+softmax+PV in LDS) =================
// 39 KB LDS -> 4 blocks/CU so co-scheduled sample blocks keep occupancy.
__device__ __forceinline__ void job_attn16(float* sm, int blk,
                                           const float* __restrict__ Qp,
                                           const float* __restrict__ Kp,
                                           const float* __restrict__ Vp,
                                           float* __restrict__ O) {
    float* S   = sm;            // [16][344]  5504
    float* KT  = sm + 5504;     // [32][68]   2176
    float* U   = sm + 7680;     // union: QT [32][20]=640 / Vt [64][32]=2048
    float* inv = sm + 9728;     // [16]
    int bh = blk & 15, qt = blk >> 4;   // qt 0..21
    int t = threadIdx.x;
    const float scale = 0.17677669529663687f;
    const float* Qb = Qp + (size_t)bh * NQ * HD;
    const float* Kb = Kp + (size_t)bh * NQ * HD;
    const float* Vb = Vp + (size_t)bh * NQ * HD;
    // stage Q^T scaled: QT[d][q], 16 rows
    if (t < 128) {
        int ql = t >> 3, d4 = (t & 7) * 4;
        int qg = qt * 16 + ql;
        float4 v = (qg < NQ) ? *(const float4*)(Qb + (size_t)qg * HD + d4)
                             : make_float4(0.f, 0.f, 0.f, 0.f);
        U[(d4 + 0) * 20 + ql] = v.x * scale;
        U[(d4 + 1) * 20 + ql] = v.y * scale;
        U[(d4 + 2) * 20 + ql] = v.z * scale;
        U[(d4 + 3) * 20 + ql] = v.w * scale;
    }
    int r = t >> 4, tx = t & 15;
    for (int kt = 0; kt < 6; ++kt) {
        __syncthreads();
        #pragma unroll
        for (int s = 0; s < 2; ++s) {
            int idx = t + s * 256;
            int kl = idx >> 3, d4 = (idx & 7) * 4;
            int kg = kt * 64 + kl;
            float4 v = (kg < NQ) ? *(const float4*)(Kb + (size_t)kg * HD + d4)
                                 : make_float4(0.f, 0.f, 0.f, 0.f);
            KT[(d4 + 0) * 68 + kl] = v.x; KT[(d4 + 1) * 68 + kl] = v.y;
            KT[(d4 + 2) * 68 + kl] = v.z; KT[(d4 + 3) * 68 + kl] = v.w;
        }
        __syncthreads();
        float a0 = 0.f, a1 = 0.f, a2 = 0.f, a3 = 0.f;
        #pragma unroll
        for (int k = 0; k < 32; ++k) {
            float qv = U[k * 20 + r];
            float4 kv = *(const float4*)&KT[k * 68 + tx * 4];
            a0 = fmaf(qv, kv.x, a0); a1 = fmaf(qv, kv.y, a1);
            a2 = fmaf(qv, kv.z, a2); a3 = fmaf(qv, kv.w, a3);
        }
        int col = kt * 64 + tx * 4;
        if (col < NQ)
            *(float4*)&S[r * 344 + col] = make_float4(a0, a1, a2, a3);
    }
    __syncthreads();
    // exact 2-pass softmax over 336 cols (16 lanes/row, 21 strided each)
    {
        float* row = S + (size_t)r * 344;
        float m = -1e30f;
        for (int i = 0; i < 21; ++i) m = fmaxf(m, row[tx + 16 * i]);
        m = fmaxf(m, __shfl_xor(m, 1));
        m = fmaxf(m, __shfl_xor(m, 2));
        m = fmaxf(m, __shfl_xor(m, 4));
        m = fmaxf(m, __shfl_xor(m, 8));
        float ssum = 0.f;
        for (int i = 0; i < 21; ++i) {
            float e = expf(row[tx + 16 * i] - m);
            row[tx + 16 * i] = e;
            ssum += e;
        }
        ssum += __shfl_xor(ssum, 1);
        ssum += __shfl_xor(ssum, 2);
        ssum += __shfl_xor(ssum, 4);
        ssum += __shfl_xor(ssum, 8);
        if (tx == 0) inv[r] = 1.f / ssum;
    }
    // PV: thread = (q row r, 2 d cols)
    int d0 = tx * 2;
    float acc0 = 0.f, acc1 = 0.f;
    for (int kt = 0; kt < 6; ++kt) {
        __syncthreads();
        #pragma unroll
        for (int s = 0; s < 2; ++s) {
            int idx = t + s * 256;
            int kl = idx >> 3, d4 = (idx & 7) * 4;
            int kg = kt * 64 + kl;
            float4 v = (kg < NQ) ? *(const float4*)(Vb + (size_t)kg * HD + d4)
                                 : make_float4(0.f, 0.f, 0.f, 0.f);
            *(float4*)&U[kl * 32 + d4] = v;   // Vt
        }
        __syncthreads();
        int kmax = (kt == 5) ? 16 : 64;
        const float* Srow = S + (size_t)r * 344 + kt * 64;
        #pragma unroll 8
        for (int kk = 0; kk < kmax; ++kk) {
            float p = Srow[kk];
            float2 vv = *(const float2*)&U[kk * 32 + d0];
            acc0 = fmaf(p, vv.x, acc0); acc1 = fmaf(p, vv.y, acc1);
        }
    }
    float iv = inv[r];
    int qg = qt * 16 + r;
    int b = bh >> 3, h = bh & 7;
    if (qg < NQ)
        *(float2*)(O + ((size_t)(b * NQ + qg)) * DD + h * HD + d0) =
            make_float2(acc0 * iv, acc1 * iv);
}

// ================= job: sample one row — thread = (view, 8-channel group) =================
template <bool TRANSPOSED>
__device__ __forceinline__ void job_sample(float* sm, int row,
                                           const float* __restrict__ f0,
                                           const float* __restrict__ f1,
                                           const float* __restrict__ f2,
                                           const float* __restrict__ refb,
                                           const float* __restrict__ Rm,
                                           const float* __restrict__ Tm,
                                           const float* __restrict__ Km,
                                           float* __restrict__ fused) {
    float* sg    = sm;           // [8][3]
    float* sPart = sm + 32;      // [8][258]
    int t = threadIdx.x;
    int b = row / NQ;
    if (t < 8) {
        int bv = b * VV + t;
        const float* r = refb + (size_t)row * 3;
        const float* R = Rm + (size_t)bv * 9;
        const float* T = Tm + (size_t)bv * 3;
        const float* K = Km + (size_t)bv * 9;
        float p0 = R[0] * r[0] + R[1] * r[1] + R[2] * r[2] + T[0];
        float p1 = R[3] * r[0] + R[4] * r[1] + R[5] * r[2] + T[1];
        float p2 = R[6] * r[0] + R[7] * r[1] + R[8] * r[2] + T[2];
        float z = fmaxf(p2, 0.1f);
        float u  = p0 * K[0] / z + K[2];
        float vv = p1 * K[4] / z + K[5];
        float un = 2.f * u  / (float)(W_IMG - 1) - 1.f;
        float vn = 2.f * vv / (float)(H_IMG - 1) - 1.f;
        bool m = (un > -1.f) && (un < 1.f) && (vn > -1.f) && (vn < 1.f) && (p2 > 0.f);
        sg[t * 3 + 0] = un; sg[t * 3 + 1] = vn; sg[t * 3 + 2] = m ? 1.f : 0.f;
    }
    __syncthreads();
    int v = t >> 5, cg = t & 31;
    int ch0 = cg * 8;
    float acc[8] = {0, 0, 0, 0, 0, 0, 0, 0};
    float m = sg[v * 3 + 2];
    if (m != 0.f) {
        float un = sg[v * 3 + 0], vn = sg[v * 3 + 1];
        int bv = b * VV + v;
        const float* fl[3] = { f0, f1, f2 };
        const int Hs[3] = { 64, 32, 16 };
        #pragma unroll
        for (int lev = 0; lev < 3; ++lev) {
            int Hh = Hs[lev], Ww = Hs[lev];
            const float* f = fl[lev];
            float xx = (un + 1.f) * Ww * 0.5f - 0.5f;
            float yy = (vn + 1.f) * Hh * 0.5f - 0.5f;
            float x0f = floorf(xx), y0f = floorf(yy);
            int ix0 = (int)x0f, iy0 = (int)y0f;
            float wx1 = xx - x0f, wx0 = 1.f - wx1;
            float wy1 = yy - y0f, wy0 = 1.f - wy1;
            #pragma unroll
            for (int tap = 0; tap < 4; ++tap) {
                int ix = ix0 + (tap & 1);
                int iy = iy0 + (tap >> 1);
                float wgt = ((tap & 1) ? wx1 : wx0) * ((tap >> 1) ? wy1 : wy0);
                if (ix >= 0 && ix < Ww && iy >= 0 && iy < Hh) {
                    if (TRANSPOSED) {
                        const float* p = f + ((size_t)bv * Hh * Ww + (size_t)iy * Ww + ix) * DD + ch0;
                        float4 va = *(const float4*)p;
                        float4 vb = *(const float4*)(p + 4);
                        acc[0] = fmaf(wgt, va.x, acc[0]); acc[1] = fmaf(wgt, va.y, acc[1]);
                        acc[2] = fmaf(wgt, va.z, acc[2]); acc[3] = fmaf(wgt, va.w, acc[3]);
                        acc[4] = fmaf(wgt, vb.x, acc[4]); acc[5] = fmaf(wgt, vb.y, acc[5]);
                        acc[6] = fmaf(wgt, vb.z, acc[6]); acc[7] = fmaf(wgt, vb.w, acc[7]);
                    } else {
                        #pragma unroll
                        for (int c = 0; c < 8; ++c) {
                            float vv2 = f[(((size_t)bv * DD + ch0 + c) * Hh + iy) * Ww + ix];
                            acc[c] = fmaf(wgt, vv2, acc[c]);
                        }
                    }
                }
            }
        }
    }
    #pragma unroll
    for (int c = 0; c < 8; ++c) sPart[v * 258 + ch0 + c] = acc[c] * (1.f / 3.f);
    __syncthreads();
    float cnt = sg[2] + sg[5] + sg[8] + sg[11] + sg[14] + sg[17] + sg[20] + sg[23];
    float s = 0.f;
    #pragma unroll
    for (int v2 = 0; v2 < 8; ++v2) s += sPart[v2 * 258 + t];
    fused[(size_t)row * DD + t] = s / fmaxf(cnt, 1.f);
}

// ================= fused dispatch B: sample (672, long-pole first) + attn16 (352) =================
template <bool TRANSPOSED>
__global__ __launch_bounds__(256) void attn_sample(const float* __restrict__ Qp,
                                                   const float* __restrict__ Kp,
                                                   const float* __restrict__ Vp,
                                                   float* __restrict__ O,
                                                   const float* __restrict__ f0,
                                                   const float* __restrict__ f1,
                                                   const float* __restrict__ f2,
                                                   const float* __restrict__ refb,
                                                   const float* __restrict__ Rm,
                                                   const float* __restrict__ Tm,
                                                   const float* __restrict__ Km,
                                                   float* __restrict__ fused) {
    __shared__ float sm[9744];   // 39 KB -> 4 blocks/CU; 1024 blocks = 4/CU exactly
    if (blockIdx.x < 672)
        job_sample<TRANSPOSED>(sm, blockIdx.x, f0, f1, f2, refb, Rm, Tm, Km, fused);
    else
        job_attn16(sm, blockIdx.x - 672, Qp, Kp, Vp, O);
}

// ================= dual row-block GEMM+LN: x = LNpn(LN1(x + O@Wo^T) + fused@Wp^T) =================
// Replaces D(oproj+res+LN1) and E(proj+res+LNpn): one launch, LN1 result via LDS.
// 2 rows x 336 blocks for TLP (r2 lesson: occupancy beats fusion at 168 blocks).
__global__ __launch_bounds__(256) void dual_gemm_ln(const float* __restrict__ attn_o,
                                                    const float* __restrict__ Wo,
                                                    const float* __restrict__ bo,
                                                    const float* __restrict__ g1,
                                                    const float* __restrict__ be1,
                                                    const float* __restrict__ fusedIn,
                                                    const float* __restrict__ Wp,
                                                    const float* __restrict__ bp,
                                                    const float* __restrict__ g2,
                                                    const float* __restrict__ be2,
                                                    float* __restrict__ x) {
    __shared__ float sA[2 * DD];
    __shared__ float sX1[2 * DD];
    __shared__ float redS[8], redS2[8], mu[2], ri[2];
    int r0 = blockIdx.x * 2;
    int j = threadIdx.x;
    ((float2*)sA)[j] = ((const float2*)(attn_o + (size_t)r0 * DD))[j];
    __syncthreads();
    // ---- stage 1: oproj + residual + LN1 -> sX1 ----
    {
        float acc0 = bo[j], acc1 = acc0;
        const float* wp = Wo + (size_t)j * DD;
        for (int k = 0; k < DD; k += 4) {
            float4 w  = *(const float4*)(wp + k);
            float4 a0 = *(const float4*)(sA + k);
            float4 a1 = *(const float4*)(sA + DD + k);
            acc0 = fmaf(a0.x, w.x, acc0); acc0 = fmaf(a0.y, w.y, acc0);
            acc0 = fmaf(a0.z, w.z, acc0); acc0 = fmaf(a0.w, w.w, acc0);
            acc1 = fmaf(a1.x, w.x, acc1); acc1 = fmaf(a1.y, w.y, acc1);
            acc1 = fmaf(a1.z, w.z, acc1); acc1 = fmaf(a1.w, w.w, acc1);
        }
        float val0 = x[(size_t)r0 * DD + j] + acc0;
        float val1 = x[(size_t)(r0 + 1) * DD + j] + acc1;
        float s0 = val0, q0 = val0 * val0, s1 = val1, q1 = val1 * val1;
        #pragma unroll
        for (int o2 = 32; o2 > 0; o2 >>= 1) {
            s0 += __shfl_xor(s0, o2); q0 += __shfl_xor(q0, o2);
            s1 += __shfl_xor(s1, o2); q1 += __shfl_xor(q1, o2);
        }
        int wid = j >> 6, lane = j & 63;
        if (lane == 0) { redS[wid] = s0; redS2[wid] = q0; redS[4 + wid] = s1; redS2[4 + wid] = q1; }
        __syncthreads();
        if (j < 2) {
            float ts  = redS[j * 4 + 0] + redS[j * 4 + 1] + redS[j * 4 + 2] + redS[j * 4 + 3];
            float ts2 = redS2[j * 4 + 0] + redS2[j * 4 + 1] + redS2[j * 4 + 2] + redS2[j * 4 + 3];
            float mean = ts * (1.f / DD);
            float var = ts2 * (1.f / DD) - mean * mean;
            mu[j] = mean; ri[j] = rsqrtf(var + 1e-5f);
        }
        __syncthreads();
        float g = g1[j], be = be1[j];
        sX1[j]      = (val0 - mu[0]) * ri[0] * g + be;
        sX1[DD + j] = (val1 - mu[1]) * ri[1] * g + be;
    }
    // all threads past their last sA read (GEMM loop before first sync) -> safe to overwrite
    ((float2*)sA)[j] = ((const float2*)(fusedIn + (size_t)r0 * DD))[j];
    __syncthreads();
    // ---- stage 2: proj + residual(sX1) + LNpn -> x ----
    {
        float acc0 = bp[j], acc1 = acc0;
        const float* wp = Wp + (size_t)j * DD;
        for (int k = 0; k < DD; k += 4) {
            float4 w  = *(const float4*)(wp + k);
            float4 a0 = *(const float4*)(sA + k);
            float4 a1 = *(const float4*)(sA + DD + k);
            acc0 = fmaf(a0.x, w.x, acc0); acc0 = fmaf(a0.y, w.y, acc0);
            acc0 = fmaf(a0.z, w.z, acc0); acc0 = fmaf(a0.w, w.w, acc0);
            acc1 = fmaf(a1.x, w.x, acc1); acc1 = fmaf(a1.y, w.y, acc1);
            acc1 = fmaf(a1.z, w.z, acc1); acc1 = fmaf(a1.w, w.w, acc1);
        }
        float val0 = sX1[j] + acc0;
        float val1 = sX1[DD + j] + acc1;
        float s0 = val0, q0 = val0 * val0, s1 = val1, q1 = val1 * val1;
        #pragma unroll
        for (int o2 = 32; o2 > 0; o2 >>= 1) {
            s0 += __shfl_xor(s0, o2); q0 += __shfl_xor(q0, o2);
            s1 += __shfl_xor(s1, o2); q1 += __shfl_xor(q1, o2);
        }
        int wid = j >> 6, lane = j & 63;
        __syncthreads();   // redS reuse: ensure stage-1 stats fully consumed
        if (lane == 0) { redS[wid] = s0; redS2[wid] = q0; redS[4 + wid] = s1; redS2[4 + wid] = q1; }
        __syncthreads();
        if (j < 2) {
            float ts  = redS[j * 4 + 0] + redS[j * 4 + 1] + redS[j * 4 + 2] + redS[j * 4 + 3];
            float ts2 = redS2[j * 4 + 0] + redS2[j * 4 + 1] + redS2[j * 4 + 2] + redS2[j * 4 + 3];
            float mean = ts * (1.f / DD);
            float var = ts2 * (1.f / DD) - mean * mean;
            mu[j] = mean; ri[j] = rsqrtf(var + 1e-5f);
        }
        __syncthreads();
        float g = g2[j], be = be2[j];
        x[(size_t)r0 * DD + j]       = (val0 - mu[0]) * ri[0] * g + be;
        x[(size_t)(r0 + 1) * DD + j] = (val1 - mu[1]) * ri[1] * g + be;
    }
}

// ================= generic tiled GEMM. MODE 0 plain, 1 relu. grid (21, N/64, KS) =================
template <int MODE>
__global__ __launch_bounds__(256) void gemm_tile(const float* __restrict__ A,
                                                 const float* __restrict__ W,
                                                 const float* __restrict__ bias,
                                                 float* __restrict__ C,
                                                 int Ktot, int Kper, int Nout) {
    __shared__ float At[32][34];
    __shared__ float Wt[32][68];
    int t = threadIdx.x;
    int m0 = blockIdx.x * 32;
    int n0 = blockIdx.y * 64;
    int kz = blockIdx.z;
    int kofs = kz * Kper;
    int tx = t & 15, ty = t >> 4;
    int nc = n0 + tx * 4;
    float acc0[4], acc1[4];
    {
        float4 bv = make_float4(0.f, 0.f, 0.f, 0.f);
        if (bias && kz == 0) bv = *(const float4*)(bias + nc);
        acc0[0] = bv.x; acc0[1] = bv.y; acc0[2] = bv.z; acc0[3] = bv.w;
        acc1[0] = bv.x; acc1[1] = bv.y; acc1[2] = bv.z; acc1[3] = bv.w;
    }
    int am = t >> 3, ak4 = (t & 7) * 4;
    int ktiles = Kper >> 5;
    for (int kt = 0; kt < ktiles; ++kt) {
        int kk = kofs + kt * 32;
        __syncthreads();
        {
            float4 v = *(const float4*)(A + (size_t)(m0 + am) * Ktot + kk + ak4);
            At[ak4 + 0][am] = v.x; At[ak4 + 1][am] = v.y;
            At[ak4 + 2][am] = v.z; At[ak4 + 3][am] = v.w;
        }
        #pragma unroll
        for (int s = 0; s < 2; ++s) {
            int idx = t + s * 256;
            int wn = idx >> 3, wk4 = (idx & 7) * 4;
            float4 v = *(const float4*)(W + (size_t)(n0 + wn) * Ktot + kk + wk4);
            Wt[wk4 + 0][wn] = v.x; Wt[wk4 + 1][wn] = v.y;
            Wt[wk4 + 2][wn] = v.z; Wt[wk4 + 3][wn] = v.w;
        }
        __syncthreads();
        #pragma unroll
        for (int k = 0; k < 32; ++k) {
            float2 av = *(const float2*)&At[k][ty * 2];
            float4 wv = *(const float4*)&Wt[k][tx * 4];
            acc0[0] = fmaf(av.x, wv.x, acc0[0]); acc0[1] = fmaf(av.x, wv.y, acc0[1]);
            acc0[2] = fmaf(av.x, wv.z, acc0[2]); acc0[3] = fmaf(av.x, wv.w, acc0[3]);
            acc1[0] = fmaf(av.y, wv.x, acc1[0]); acc1[1] = fmaf(av.y, wv.y, acc1[1]);
            acc1[2] = fmaf(av.y, wv.z, acc1[2]); acc1[3] = fmaf(av.y, wv.w, acc1[3]);
        }
    }
    if (MODE == 1) {
        #pragma unroll
        for (int j = 0; j < 4; ++j) { acc0[j] = fmaxf(acc0[j], 0.f); acc1[j] = fmaxf(acc1[j], 0.f); }
    }
    int mr = m0 + ty * 2;
    float* Cb = C + (size_t)kz * MROWS * Nout;
    *(float4*)(Cb + (size_t)mr * Nout + nc)       = make_float4(acc0[0], acc0[1], acc0[2], acc0[3]);
    *(float4*)(Cb + (size_t)(mr + 1) * Nout + nc) = make_float4(acc1[0], acc1[1], acc1[2], acc1[3]);
}

// ================= residual + LN over NP k-split partials; xq = out + qp =================
template <int NP>
__global__ __launch_bounds__(256) void ln_res(float* __restrict__ x,
                                              const float* __restrict__ C,
                                              const float* __restrict__ gam,
                                              const float* __restrict__ bet,
                                              const float* __restrict__ qp,
                                              float* __restrict__ xq) {
    __shared__ float redS[4][4], redS2[4][4];
    __shared__ float mu[4], ri[4];
    int r0 = blockIdx.x * 4;
    int j = threadIdx.x;
    float val[4];
    #pragma unroll
    for (int r = 0; r < 4; ++r) {
        float a = x[(size_t)(r0 + r) * DD + j];
        #pragma unroll
        for (int p = 0; p < NP; ++p) a += C[(size_t)p * MROWS * DD + (size_t)(r0 + r) * DD + j];
        val[r] = a;
    }
    float s[4], s2[4];
    #pragma unroll
    for (int r = 0; r < 4; ++r) { s[r] = val[r]; s2[r] = val[r] * val[r]; }
    #pragma unroll
    for (int o = 32; o > 0; o >>= 1) {
        #pragma unroll
        for (int r = 0; r < 4; ++r) {
            s[r]  += __shfl_xor(s[r],  o);
            s2[r] += __shfl_xor(s2[r], o);
        }
    }
    int wid = j >> 6, lane = j & 63;
    if (lane == 0) {
        #pragma unroll
        for (int r = 0; r < 4; ++r) { redS[r][wid] = s[r]; redS2[r][wid] = s2[r]; }
    }
    __syncthreads();
    if (j < 4) {
        int r = j;
        float ts  = redS[r][0]  + redS[r][1]  + redS[r][2]  + redS[r][3];
        float ts2 = redS2[r][0] + redS2[r][1] + redS2[r][2] + redS2[r][3];
        float mean = ts * (1.f / DD);
        float var = ts2 * (1.f / DD) - mean * mean;
        mu[r] = mean;
        ri[r] = rsqrtf(var + 1e-5f);
    }
    __syncthreads();
    float g = gam[j], be = bet[j];
    #pragma unroll
    for (int r = 0; r < 4; ++r) {
        float o = (val[r] - mu[r]) * ri[r] * g + be;
        x[(size_t)(r0 + r) * DD + j] = o;
        if (qp) xq[(size_t)(r0 + r) * DD + j] = o + qp[(size_t)(r0 + r) * DD + j];
    }
}

extern "C" void kernel_launch(void* const* d_in, const int* in_sizes, int n_in,
                              void* d_out, int out_size, void* d_ws, size_t ws_size,
                              hipStream_t stream) {
    const float* tgt       = (const float*)d_in[0];
    const float* query_pos = (const float*)d_in[1];
    const float* refpts    = (const float*)d_in[2];
    const float* feat0     = (const float*)d_in[3];
    const float* feat1     = (const float*)d_in[4];
    const float* feat2     = (const float*)d_in[5];
    const float* camR      = (const float*)d_in[6];
    const float* camT      = (const float*)d_in[7];
    const float* camK      = (const float*)d_in[8];
    const float* Wqkv      = (const float*)d_in[9];
    const float* bqkv      = (const float*)d_in[10];
    const float* Wo        = (const float*)d_in[11];
    const float* bo        = (const float*)d_in[12];
    const float* ln1_g     = (const float*)d_in[13];
    const float* ln1_b     = (const float*)d_in[14];
    const float* Wproj     = (const float*)d_in[15];
    const float* bproj     = (const float*)d_in[16];
    const float* pn_g      = (const float*)d_in[17];
    const float* pn_b      = (const float*)d_in[18];
    const float* W1        = (const float*)d_in[19];
    const float* b1        = (const float*)d_in[20];
    const float* W2        = (const float*)d_in[21];
    const float* b2        = (const float*)d_in[22];
    const float* ln2_g     = (const float*)d_in[23];
    const float* ln2_b     = (const float*)d_in[24];
    const float* pose_W0   = (const float*)d_in[25];
    const float* pose_b0   = (const float*)d_in[26];
    const float* pose_W1   = (const float*)d_in[27];
    const float* pose_b1   = (const float*)d_in[28];
    const float* pose_W2   = (const float*)d_in[29];
    const float* pose_b2   = (const float*)d_in[30];
    const float* cls_W     = (const float*)d_in[31];
    const float* cls_b     = (const float*)d_in[32];
    float* out = (float*)d_out;

    float* w = (float*)d_ws;
    size_t off = 0;
    auto alloc = [&](size_t n) { float* p = w + off; off += n; return p; };
    float* x      = alloc((size_t)BQ * DD);
    float* xq     = alloc((size_t)BQ * DD);
    float* Qp     = alloc((size_t)BB * HEADS * NQ * HD);
    float* Kp     = alloc((size_t)BB * HEADS * NQ * HD);
    float* Vp     = alloc((size_t)BB * HEADS * NQ * HD);
    float* attn_o = alloc((size_t)BQ * DD);
    float* fused  = alloc((size_t)BQ * DD);
    float* ffh    = alloc((size_t)BQ * FF);
    float* ctmp   = alloc((size_t)4 * BQ * DD);
    float* refb   = alloc((size_t)BQ * 3 + 64);
    size_t base_floats = off;
    size_t featT_floats = (size_t)BB * VV * DD * (64 * 64 + 32 * 32 + 16 * 16);
    bool useT = ws_size >= (base_floats + featT_floats) * sizeof(float);
    float *fT0 = nullptr, *fT1 = nullptr, *fT2 = nullptr;
    if (useT) {
        fT0 = alloc((size_t)BB * VV * 64 * 64 * DD);
        fT1 = alloc((size_t)BB * VV * 32 * 32 * DD);
        fT2 = alloc((size_t)BB * VV * 16 * 16 * DD);
    }

    // init x, xq, refb (168 blocks). Separate dispatch: layer-0 qkv reads xq.
    init_k<<<168, 256, 0, stream>>>(tgt, query_pos, refpts, x, xq, refb);

    for (int l = 0; l < NL; ++l) {
        // A: qkv (252) + [l==0: full feature transpose (5376)] / [l>0: pose head (168)]
        if (l == 0 && useT) {
            qkv_tr<<<252 + 5376, 256, 0, stream>>>(
                xq, x, Wqkv, bqkv, Qp, Kp, Vp,
                feat0, feat1, feat2, fT0, fT1, fT2);
        } else {
            qkv_pose<<<252 + (l > 0 ? 168 : 0), 256, 0, stream>>>(
                xq, x, Wqkv + (size_t)l * 3 * DD * DD, bqkv + (size_t)l * 3 * DD, Qp, Kp, Vp,
                pose_W0, pose_b0, pose_W1, pose_b1, pose_W2, pose_b2, cls_W, cls_b,
                refb, out + (size_t)(l - 1) * BQ * 4);
        }
        // B: sample (672) + attn16 (352) — gather overlaps attention compute
        if (useT)
            attn_sample<true><<<1024, 256, 0, stream>>>(
                Qp, Kp, Vp, attn_o, fT0, fT1, fT2, refb, camR, camT, camK, fused);
        else
            attn_sample<false><<<1024, 256, 0, stream>>>(
                Qp, Kp, Vp, attn_o, feat0, feat1, feat2, refb, camR, camT, camK, fused);
        // C: oproj+res+LN1 then proj+res+LNpn, fused (336 blocks x 2 rows)
        dual_gemm_ln<<<336, 256, 0, stream>>>(
            attn_o, Wo + (size_t)l * DD * DD, bo + (size_t)l * DD,
            ln1_g + (size_t)l * DD, ln1_b + (size_t)l * DD,
            fused, Wproj + (size_t)l * DD * DD, bproj + (size_t)l * DD,
            pn_g + (size_t)l * DD, pn_b + (size_t)l * DD, x);
        // FFN1 (relu)
        gemm_tile<1><<<dim3(21, 16, 1), 256, 0, stream>>>(
            x, W1 + (size_t)l * FF * DD, b1 + (size_t)l * FF, ffh, DD, DD, FF);
        // FFN2 k-split (336 blocks) + ln_res (168): occupancy beats fusion here (r2).
        gemm_tile<0><<<dim3(21, 4, 4), 256, 0, stream>>>(
            ffh, W2 + (size_t)l * DD * FF, b2 + (size_t)l * DD, ctmp, FF, FF / 4, DD);
        ln_res<4><<<BQ / 4, 256, 0, stream>>>(
            x, ctmp, ln2_g + (size_t)l * DD, ln2_b + (size_t)l * DD, query_pos, xq);
    }
    // tail: pose head of layer NL-1
    pose_only<<<BQ / 4, 256, 0, stream>>>(
        x, pose_W0, pose_b0, pose_W1, pose_b1, pose_W2, pose_b2, cls_W, cls_b,
        refb, out + (size_t)(NL - 1) * BQ * 4);
}

// Round 6
// 858.929 us; speedup vs baseline: 1.0790x; 1.0790x over previous
//
#include <hip/hip_runtime.h>
#include <math.h>

#define BB 2
#define VV 8
#define NQ 336
#define DD 256
#define HEADS 8
#define HD 32
#define FF 1024
#define NL 6
#define BQ (BB*NQ)
#define W_IMG 512
#define H_IMG 512
#define MROWS BQ

// ================= job: 128ch x 32px transpose tile (5376 tiles) =================
// 16.9 KB LDS -> 8 blocks/CU (wave-capped). 512B-contiguous channel writes.
// At 7.7 TB/s combined fabric throughput (r3 counters) — memory-system-limited.
__device__ __forceinline__ void job_transpose3(float* tile, int b,
                                               const float* __restrict__ f0,
                                               const float* __restrict__ f1,
                                               const float* __restrict__ f2,
                                               float* __restrict__ o0,
                                               float* __restrict__ o1,
                                               float* __restrict__ o2) {
    const float* src; float* dst; int HW, ptiles;
    if (b < 4096)      { src = f0; dst = o0; HW = 4096; ptiles = 128; }
    else if (b < 5120) { b -= 4096; src = f1; dst = o1; HW = 1024; ptiles = 32; }
    else               { b -= 5120; src = f2; dst = o2; HW = 256;  ptiles = 8;  }
    int cg = b & 1;
    int pt = (b >> 1) % ptiles;
    int bv = (b >> 1) / ptiles;
    int d0 = cg * 128, p0 = pt * 32;
    int t = threadIdx.x;
    int chb = t >> 3, px4 = (t & 7) * 4;
    #pragma unroll
    for (int pass = 0; pass < 4; ++pass) {
        int ch = pass * 32 + chb;
        float4 v = *(const float4*)(src + ((size_t)(bv * DD + d0 + ch)) * HW + p0 + px4);
        tile[ch * 33 + px4 + 0] = v.x; tile[ch * 33 + px4 + 1] = v.y;
        tile[ch * 33 + px4 + 2] = v.z; tile[ch * 33 + px4 + 3] = v.w;
    }
    __syncthreads();
    int c4 = (t & 31) * 4, pxb = t >> 5;
    #pragma unroll
    for (int pass = 0; pass < 4; ++pass) {
        int px = pass * 8 + pxb;
        float4 o;
        o.x = tile[(c4 + 0) * 33 + px];
        o.y = tile[(c4 + 1) * 33 + px];
        o.z = tile[(c4 + 2) * 33 + px];
        o.w = tile[(c4 + 3) * 33 + px];
        *(float4*)(dst + ((size_t)bv * HW + p0 + px) * DD + d0 + c4) = o;
    }
}

// ================= init (168 blocks) =================
__global__ __launch_bounds__(256) void init_k(const float* __restrict__ tgt,
                                              const float* __restrict__ qp,
                                              const float* __restrict__ refpts,
                                              float* __restrict__ x,
                                              float* __restrict__ xq,
                                              float* __restrict__ refb) {
    int i = blockIdx.x * 256 + threadIdx.x;
    float4 tv = ((const float4*)tgt)[i];
    float4 qv = ((const float4*)qp)[i];
    ((float4*)x)[i] = tv;
    ((float4*)xq)[i] = make_float4(tv.x + qv.x, tv.y + qv.y, tv.z + qv.z, tv.w + qv.w);
    if (i < BQ * 3) refb[i] = refpts[i];
}

// ================= job: 32x64 qkv tile, head-packed output =================
__device__ __forceinline__ void job_qkv(float* sm, int bid,
                                        const float* __restrict__ Aq,
                                        const float* __restrict__ Ax,
                                        const float* __restrict__ W,
                                        const float* __restrict__ bias,
                                        float* __restrict__ Qp,
                                        float* __restrict__ Kp,
                                        float* __restrict__ Vp) {
    float* At = sm;            // [32][34]
    float* Wt = sm + 1088;     // [32][68]
    int t = threadIdx.x;
    int m0 = (bid % 21) * 32;
    int ncol = bid / 21;
    int n0 = ncol * 64;
    const float* A = (ncol < 8) ? Aq : Ax;
    int tx = t & 15, ty = t >> 4;
    int nc = n0 + tx * 4;
    float acc0[4], acc1[4];
    {
        float4 bv = *(const float4*)(bias + nc);
        acc0[0] = bv.x; acc0[1] = bv.y; acc0[2] = bv.z; acc0[3] = bv.w;
        acc1[0] = bv.x; acc1[1] = bv.y; acc1[2] = bv.z; acc1[3] = bv.w;
    }
    int am = t >> 3, ak4 = (t & 7) * 4;
    for (int kt = 0; kt < 8; ++kt) {
        int kk = kt * 32;
        __syncthreads();
        {
            float4 v = *(const float4*)(A + (size_t)(m0 + am) * DD + kk + ak4);
            At[(ak4 + 0) * 34 + am] = v.x; At[(ak4 + 1) * 34 + am] = v.y;
            At[(ak4 + 2) * 34 + am] = v.z; At[(ak4 + 3) * 34 + am] = v.w;
        }
        #pragma unroll
        for (int s = 0; s < 2; ++s) {
            int idx = t + s * 256;
            int wn = idx >> 3, wk4 = (idx & 7) * 4;
            float4 v = *(const float4*)(W + (size_t)(n0 + wn) * DD + kk + wk4);
            Wt[(wk4 + 0) * 68 + wn] = v.x; Wt[(wk4 + 1) * 68 + wn] = v.y;
            Wt[(wk4 + 2) * 68 + wn] = v.z; Wt[(wk4 + 3) * 68 + wn] = v.w;
        }
        __syncthreads();
        #pragma unroll
        for (int k = 0; k < 32; ++k) {
            float2 av = *(const float2*)&At[k * 34 + ty * 2];
            float4 wv = *(const float4*)&Wt[k * 68 + tx * 4];
            acc0[0] = fmaf(av.x, wv.x, acc0[0]); acc0[1] = fmaf(av.x, wv.y, acc0[1]);
            acc0[2] = fmaf(av.x, wv.z, acc0[2]); acc0[3] = fmaf(av.x, wv.w, acc0[3]);
            acc1[0] = fmaf(av.y, wv.x, acc1[0]); acc1[1] = fmaf(av.y, wv.y, acc1[1]);
            acc1[2] = fmaf(av.y, wv.z, acc1[2]); acc1[3] = fmaf(av.y, wv.w, acc1[3]);
        }
    }
    int mr = m0 + ty * 2;
    int kind = nc >> 8;
    float* base = kind == 0 ? Qp : (kind == 1 ? Kp : Vp);
    int h = (nc >> 5) & 7, d4 = nc & 31;
    #pragma unroll
    for (int i = 0; i < 2; ++i) {
        int m = mr + i;
        int b = m / NQ, q = m - b * NQ;
        float* p = base + ((size_t)((b << 3) + h) * NQ + q) * HD + d4;
        float* src = i == 0 ? acc0 : acc1;
        *(float4*)p = make_float4(src[0], src[1], src[2], src[3]);
    }
}

// ================= job: pose MLP + heads for 4 rows =================
__device__ __forceinline__ void job_pose(float* sm, int job,
                                         const float* __restrict__ x,
                                         const float* __restrict__ W0, const float* __restrict__ b0,
                                         const float* __restrict__ W1p, const float* __restrict__ b1p,
                                         const float* __restrict__ W2p, const float* __restrict__ b2p,
                                         const float* __restrict__ cW, const float* __restrict__ cb,
                                         float* __restrict__ refb, float* __restrict__ outp) {
    float* sX  = sm;          // 1024
    float* sH  = sm + 1024;   // 1024
    float* red = sm + 2048;   // 64
    int r0 = job * 4;
    int tid = threadIdx.x;
    ((float4*)sX)[tid] = ((const float4*)(x + (size_t)r0 * DD))[tid];
    __syncthreads();
    {
        float a0 = b0[tid], a1 = a0, a2 = a0, a3 = a0;
        const float* wp = W0 + (size_t)tid * DD;
        for (int k = 0; k < DD; k += 4) {
            float4 w  = *(const float4*)(wp + k);
            float4 x0 = *(const float4*)(sX + 0 * DD + k);
            float4 x1 = *(const float4*)(sX + 1 * DD + k);
            float4 x2 = *(const float4*)(sX + 2 * DD + k);
            float4 x3 = *(const float4*)(sX + 3 * DD + k);
            a0 = fmaf(x0.x, w.x, a0); a0 = fmaf(x0.y, w.y, a0); a0 = fmaf(x0.z, w.z, a0); a0 = fmaf(x0.w, w.w, a0);
            a1 = fmaf(x1.x, w.x, a1); a1 = fmaf(x1.y, w.y, a1); a1 = fmaf(x1.z, w.z, a1); a1 = fmaf(x1.w, w.w, a1);
            a2 = fmaf(x2.x, w.x, a2); a2 = fmaf(x2.y, w.y, a2); a2 = fmaf(x2.z, w.z, a2); a2 = fmaf(x2.w, w.w, a2);
            a3 = fmaf(x3.x, w.x, a3); a3 = fmaf(x3.y, w.y, a3); a3 = fmaf(x3.z, w.z, a3); a3 = fmaf(x3.w, w.w, a3);
        }
        sH[0 * DD + tid] = fmaxf(a0, 0.f);
        sH[1 * DD + tid] = fmaxf(a1, 0.f);
        sH[2 * DD + tid] = fmaxf(a2, 0.f);
        sH[3 * DD + tid] = fmaxf(a3, 0.f);
    }
    __syncthreads();
    float h[4];
    {
        float a0 = b1p[tid], a1 = a0, a2 = a0, a3 = a0;
        const float* wp = W1p + (size_t)tid * DD;
        for (int k = 0; k < DD; k += 4) {
            float4 w  = *(const float4*)(wp + k);
            float4 x0 = *(const float4*)(sH + 0 * DD + k);
            float4 x1 = *(const float4*)(sH + 1 * DD + k);
            float4 x2 = *(const float4*)(sH + 2 * DD + k);
            float4 x3 = *(const float4*)(sH + 3 * DD + k);
            a0 = fmaf(x0.x, w.x, a0); a0 = fmaf(x0.y, w.y, a0); a0 = fmaf(x0.z, w.z, a0); a0 = fmaf(x0.w, w.w, a0);
            a1 = fmaf(x1.x, w.x, a1); a1 = fmaf(x1.y, w.y, a1); a1 = fmaf(x1.z, w.z, a1); a1 = fmaf(x1.w, w.w, a1);
            a2 = fmaf(x2.x, w.x, a2); a2 = fmaf(x2.y, w.y, a2); a2 = fmaf(x2.z, w.z, a2); a2 = fmaf(x2.w, w.w, a2);
            a3 = fmaf(x3.x, w.x, a3); a3 = fmaf(x3.y, w.y, a3); a3 = fmaf(x3.z, w.z, a3); a3 = fmaf(x3.w, w.w, a3);
        }
        h[0] = fmaxf(a0, 0.f); h[1] = fmaxf(a1, 0.f); h[2] = fmaxf(a2, 0.f); h[3] = fmaxf(a3, 0.f);
    }
    float w2a = W2p[tid], w2b = W2p[DD + tid], w2c = W2p[2 * DD + tid], cw = cW[tid];
    float v[4][4];
    #pragma unroll
    for (int r = 0; r < 4; ++r) {
        v[r][0] = h[r] * w2a;
        v[r][1] = h[r] * w2b;
        v[r][2] = h[r] * w2c;
        v[r][3] = sX[r * DD + tid] * cw;
    }
    #pragma unroll
    for (int o2 = 32; o2 > 0; o2 >>= 1) {
        #pragma unroll
        for (int r = 0; r < 4; ++r) {
            #pragma unroll
            for (int c = 0; c < 4; ++c) v[r][c] += __shfl_xor(v[r][c], o2);
        }
    }
    int wid = tid >> 6, lane = tid & 63;
    if (lane == 0) {
        #pragma unroll
        for (int r = 0; r < 4; ++r) {
            #pragma unroll
            for (int c = 0; c < 4; ++c) red[(r * 4 + c) * 4 + wid] = v[r][c];
        }
    }
    __syncthreads();
    if (tid < 4) {
        int r = tid;
        float d0 = red[(r * 4 + 0) * 4 + 0] + red[(r * 4 + 0) * 4 + 1] + red[(r * 4 + 0) * 4 + 2] + red[(r * 4 + 0) * 4 + 3] + b2p[0];
        float d1 = red[(r * 4 + 1) * 4 + 0] + red[(r * 4 + 1) * 4 + 1] + red[(r * 4 + 1) * 4 + 2] + red[(r * 4 + 1) * 4 + 3] + b2p[1];
        float d2 = red[(r * 4 + 2) * 4 + 0] + red[(r * 4 + 2) * 4 + 1] + red[(r * 4 + 2) * 4 + 2] + red[(r * 4 + 2) * 4 + 3] + b2p[2];
        float cl = red[(r * 4 + 3) * 4 + 0] + red[(r * 4 + 3) * 4 + 1] + red[(r * 4 + 3) * 4 + 2] + red[(r * 4 + 3) * 4 + 3] + cb[0];
        int row = r0 + r;
        float rx = refb[(size_t)row * 3 + 0] + d0;
        float ry = refb[(size_t)row * 3 + 1] + d1;
        float rz = refb[(size_t)row * 3 + 2] + d2;
        refb[(size_t)row * 3 + 0] = rx;
        refb[(size_t)row * 3 + 1] = ry;
        refb[(size_t)row * 3 + 2] = rz;
        outp[(size_t)row * 4 + 0] = cl;
        outp[(size_t)row * 4 + 1] = rx;
        outp[(size_t)row * 4 + 2] = ry;
        outp[(size_t)row * 4 + 3] = rz;
    }
}

// ================= fused dispatch A: qkv (252) + pose of prev layer (168) =================
__global__ __launch_bounds__(256) void qkv_pose(const float* __restrict__ xq,
                                                const float* __restrict__ x,
                                                const float* __restrict__ Wqkv,
                                                const float* __restrict__ bqkv,
                                                float* __restrict__ Qp,
                                                float* __restrict__ Kp,
                                                float* __restrict__ Vp,
                                                const float* __restrict__ pW0, const float* __restrict__ pb0,
                                                const float* __restrict__ pW1, const float* __restrict__ pb1,
                                                const float* __restrict__ pW2, const float* __restrict__ pb2,
                                                const float* __restrict__ cW, const float* __restrict__ cb,
                                                float* __restrict__ refb, float* __restrict__ outp) {
    __shared__ float sm[3264];
    if (blockIdx.x < 252)
        job_qkv(sm, blockIdx.x, xq, x, Wqkv, bqkv, Qp, Kp, Vp);
    else
        job_pose(sm, blockIdx.x - 252, x, pW0, pb0, pW1, pb1, pW2, pb2, cW, cb, refb, outp);
}

// ================= layer-0 variant: qkv (252) + full transpose (5376) =================
__global__ __launch_bounds__(256) void qkv_tr(const float* __restrict__ xq,
                                              const float* __restrict__ x,
                                              const float* __restrict__ Wqkv,
                                              const float* __restrict__ bqkv,
                                              float* __restrict__ Qp,
                                              float* __restrict__ Kp,
                                              float* __restrict__ Vp,
                                              const float* __restrict__ f0,
                                              const float* __restrict__ f1,
                                              const float* __restrict__ f2,
                                              float* __restrict__ o0,
                                              float* __restrict__ o1,
                                              float* __restrict__ o2) {
    __shared__ float sm[4224];
    if (blockIdx.x < 252)
        job_qkv(sm, blockIdx.x, xq, x, Wqkv, bqkv, Qp, Kp, Vp);
    else
        job_transpose3(sm, blockIdx.x - 252, f0, f1, f2, o0, o1, o2);
}

// standalone pose (tail)
__global__ __launch_bounds__(256) void pose_only(const float* __restrict__ x,
                                                 const float* __restrict__ pW0, const float* __restrict__ pb0,
                                                 const float* __restrict__ pW1, const float* __restrict__ pb1,
                                                 const float* __restrict__ pW2, const float* __restrict__ pb2,
                                                 const float* __restrict__ cW, const float* __restrict__ cb,
                                                 float* __restrict__ refb, float* __restrict__ outp) {
    __shared__ float sm[2112];
    job_pose(sm, blockIdx.x, x, pW0, pb0, pW1, pb1, pW2, pb2, cW, cb, refb, outp);
}

// ================= fused attention: scores + exact softmax + PV, S strip in LDS =================
// grid: 176 blocks (16 bh x 11 q-tiles of 32 rows). Pure attn; 61 KB static LDS.
__global__ __launch_bounds__(256) void attn_fused(const float* __restrict__ Qp,
                                                  const float* __restrict__ Kp,
                                                  const float* __restrict__ Vp,
                                                  float* __restrict__ O) {
    __shared__ float sm[15264];
    float* S   = sm;            // [32][344]
    float* KT  = sm + 11008;    // [32][68]
    float* U   = sm + 13184;    // union: QT [32][36] (scores) / Vt [64][32] (PV)
    float* inv = sm + 15232;    // [32]
    int blk = blockIdx.x;
    int bh = blk & 15, qt = blk >> 4;
    int t = threadIdx.x;
    const float scale = 0.17677669529663687f;
    const float* Qb = Qp + (size_t)bh * NQ * HD;
    const float* Kb = Kp + (size_t)bh * NQ * HD;
    const float* Vb = Vp + (size_t)bh * NQ * HD;
    // stage Q tile transposed+scaled: QT[d][q]
    {
        int ql = t >> 3, d4 = (t & 7) * 4;
        int qg = qt * 32 + ql;
        float4 v = (qg < NQ) ? *(const float4*)(Qb + (size_t)qg * HD + d4)
                             : make_float4(0.f, 0.f, 0.f, 0.f);
        U[(d4 + 0) * 36 + ql] = v.x * scale;
        U[(d4 + 1) * 36 + ql] = v.y * scale;
        U[(d4 + 2) * 36 + ql] = v.z * scale;
        U[(d4 + 3) * 36 + ql] = v.w * scale;
    }
    int tx = t & 15, ty = t >> 4;
    for (int kt = 0; kt < 6; ++kt) {
        __syncthreads();
        #pragma unroll
        for (int s = 0; s < 2; ++s) {
            int idx = t + s * 256;
            int kl = idx >> 3, d4 = (idx & 7) * 4;
            int kg = kt * 64 + kl;
            float4 v = (kg < NQ) ? *(const float4*)(Kb + (size_t)kg * HD + d4)
                                 : make_float4(0.f, 0.f, 0.f, 0.f);
            KT[(d4 + 0) * 68 + kl] = v.x; KT[(d4 + 1) * 68 + kl] = v.y;
            KT[(d4 + 2) * 68 + kl] = v.z; KT[(d4 + 3) * 68 + kl] = v.w;
        }
        __syncthreads();
        float a0[4] = {0, 0, 0, 0}, a1[4] = {0, 0, 0, 0};
        #pragma unroll
        for (int k = 0; k < 32; ++k) {
            float2 qv = *(const float2*)&U[k * 36 + ty * 2];
            float4 kv = *(const float4*)&KT[k * 68 + tx * 4];
            a0[0] = fmaf(qv.x, kv.x, a0[0]); a0[1] = fmaf(qv.x, kv.y, a0[1]);
            a0[2] = fmaf(qv.x, kv.z, a0[2]); a0[3] = fmaf(qv.x, kv.w, a0[3]);
            a1[0] = fmaf(qv.y, kv.x, a1[0]); a1[1] = fmaf(qv.y, kv.y, a1[1]);
            a1[2] = fmaf(qv.y, kv.z, a1[2]); a1[3] = fmaf(qv.y, kv.w, a1[3]);
        }
        int col = kt * 64 + tx * 4;
        if (col < NQ) {
            *(float4*)&S[(ty * 2 + 0) * 344 + col] = make_float4(a0[0], a0[1], a0[2], a0[3]);
            *(float4*)&S[(ty * 2 + 1) * 344 + col] = make_float4(a1[0], a1[1], a1[2], a1[3]);
        }
    }
    __syncthreads();
    // exact 2-pass softmax, exp stored unnormalized; 1/sum folded into output write
    {
        int r = t >> 3, cg = t & 7;
        float* row = S + (size_t)r * 344;
        float m = -1e30f;
        for (int i = 0; i < 42; ++i) m = fmaxf(m, row[cg + 8 * i]);
        m = fmaxf(m, __shfl_xor(m, 1));
        m = fmaxf(m, __shfl_xor(m, 2));
        m = fmaxf(m, __shfl_xor(m, 4));
        float ssum = 0.f;
        for (int i = 0; i < 42; ++i) {
            float e = expf(row[cg + 8 * i] - m);
            row[cg + 8 * i] = e;
            ssum += e;
        }
        ssum += __shfl_xor(ssum, 1);
        ssum += __shfl_xor(ssum, 2);
        ssum += __shfl_xor(ssum, 4);
        if (cg == 0) inv[r] = 1.f / ssum;
    }
    // PV: each thread one q row x 4 d cols
    int q = t >> 3, d0 = (t & 7) * 4;
    float acc[4] = {0, 0, 0, 0};
    for (int kt = 0; kt < 6; ++kt) {
        __syncthreads();
        #pragma unroll
        for (int s = 0; s < 2; ++s) {
            int idx = t + s * 256;
            int kl = idx >> 3, d4 = (idx & 7) * 4;
            int kg = kt * 64 + kl;
            float4 v = (kg < NQ) ? *(const float4*)(Vb + (size_t)kg * HD + d4)
                                 : make_float4(0.f, 0.f, 0.f, 0.f);
            *(float4*)&U[kl * 32 + d4] = v;   // Vt
        }
        __syncthreads();
        int kmax = (kt == 5) ? 16 : 64;       // keys 320..335 only (NQ=336)
        const float* Srow = S + (size_t)q * 344 + kt * 64;
        #pragma unroll 8
        for (int kk = 0; kk < kmax; ++kk) {
            float p = Srow[kk];
            float4 vv = *(const float4*)&U[kk * 32 + d0];
            acc[0] = fmaf(p, vv.x, acc[0]); acc[1] = fmaf(p, vv.y, acc[1]);
            acc[2] = fmaf(p, vv.z, acc[2]); acc[3] = fmaf(p, vv.w, acc[3]);
        }
    }
    float iv = inv[q];
    int qg = qt * 32 + q;
    int b = bh >> 3, h = bh & 7;
    if (qg < NQ)
        *(float4*)(O + ((size_t)(b * NQ + qg)) * DD + h * HD + d0) =
            make_float4(acc[0] * iv, acc[1] * iv, acc[2] * iv, acc[3] * iv);
}

// ================= job: row-block GEMM(K=256,N=256) + residual + LN (4 rows) =================
__device__ __forceinline__ void job_gemm_ln(float* sm, int r0,
                                            const float* __restrict__ A,
                                            const float* __restrict__ Wt,
                                            const float* __restrict__ bias,
                                            const float* __restrict__ gam,
                                            const float* __restrict__ bet,
                                            float* __restrict__ x) {
    float* sA    = sm;          // 1024
    float* redS  = sm + 1024;   // 16
    float* redS2 = sm + 1040;   // 16
    float* mu    = sm + 1056;   // 4
    float* ri    = sm + 1060;   // 4
    int j = threadIdx.x;
    ((float4*)sA)[j] = ((const float4*)(A + (size_t)r0 * DD))[j];
    __syncthreads();
    float acc0 = bias[j], acc1 = acc0, acc2 = acc0, acc3 = acc0;
    const float* wp = Wt + (size_t)j * DD;
    for (int k = 0; k < DD; k += 4) {
        float4 w  = *(const float4*)(wp + k);
        float4 a0 = *(const float4*)(sA + 0 * DD + k);
        float4 a1 = *(const float4*)(sA + 1 * DD + k);
        float4 a2 = *(const float4*)(sA + 2 * DD + k);
        float4 a3 = *(const float4*)(sA + 3 * DD + k);
        acc0 = fmaf(a0.x, w.x, acc0); acc0 = fmaf(a0.y, w.y, acc0); acc0 = fmaf(a0.z, w.z, acc0); acc0 = fmaf(a0.w, w.w, acc0);
        acc1 = fmaf(a1.x, w.x, acc1); acc1 = fmaf(a1.y, w.y, acc1); acc1 = fmaf(a1.z, w.z, acc1); acc1 = fmaf(a1.w, w.w, acc1);
        acc2 = fmaf(a2.x, w.x, acc2); acc2 = fmaf(a2.y, w.y, acc2); acc2 = fmaf(a2.z, w.z, acc2); acc2 = fmaf(a2.w, w.w, acc2);
        acc3 = fmaf(a3.x, w.x, acc3); acc3 = fmaf(a3.y, w.y, acc3); acc3 = fmaf(a3.z, w.z, acc3); acc3 = fmaf(a3.w, w.w, acc3);
    }
    float val[4];
    val[0] = x[(size_t)(r0 + 0) * DD + j] + acc0;
    val[1] = x[(size_t)(r0 + 1) * DD + j] + acc1;
    val[2] = x[(size_t)(r0 + 2) * DD + j] + acc2;
    val[3] = x[(size_t)(r0 + 3) * DD + j] + acc3;
    float s[4], s2[4];
    #pragma unroll
    for (int r = 0; r < 4; ++r) { s[r] = val[r]; s2[r] = val[r] * val[r]; }
    #pragma unroll
    for (int o2 = 32; o2 > 0; o2 >>= 1) {
        #pragma unroll
        for (int r = 0; r < 4; ++r) {
            s[r]  += __shfl_xor(s[r],  o2);
            s2[r] += __shfl_xor(s2[r], o2);
        }
    }
    int wid = j >> 6, lane = j & 63;
    if (lane == 0) {
        #pragma unroll
        for (int r = 0; r < 4; ++r) { redS[r * 4 + wid] = s[r]; redS2[r * 4 + wid] = s2[r]; }
    }
    __syncthreads();
    if (j < 4) {
        int r = j;
        float ts  = redS[r * 4 + 0]  + redS[r * 4 + 1]  + redS[r * 4 + 2]  + redS[r * 4 + 3];
        float ts2 = redS2[r * 4 + 0] + redS2[r * 4 + 1] + redS2[r * 4 + 2] + redS2[r * 4 + 3];
        float mean = ts * (1.f / DD);
        float var = ts2 * (1.f / DD) - mean * mean;
        mu[r] = mean;
        ri[r] = rsqrtf(var + 1e-5f);
    }
    __syncthreads();
    float g = gam[j], be = bet[j];
    #pragma unroll
    for (int r = 0; r < 4; ++r)
        x[(size_t)(r0 + r) * DD + j] = (val[r] - mu[r]) * ri[r] * g + be;
}

// ================= proj-GEMM + res + LN, 2 rows x 336 blocks =================
// Replaces the 168-block 4-row version: latency-bound row-GEMM gains 2x TLP
// (0.66 -> 1.3 blocks/CU); W L2 traffic 43->86 MB, still << L2 BW limit.
__global__ __launch_bounds__(256) void gemm2_res_ln(const float* __restrict__ A,
                                                    const float* __restrict__ Wt,
                                                    const float* __restrict__ bias,
                                                    const float* __restrict__ gam,
                                                    const float* __restrict__ bet,
                                                    float* __restrict__ x) {
    __shared__ float sA[2 * DD];
    __shared__ float redS[8], redS2[8], mu[2], ri[2];
    int r0 = blockIdx.x * 2;
    int j = threadIdx.x;
    ((float2*)sA)[j] = ((const float2*)(A + (size_t)r0 * DD))[j];
    __syncthreads();
    float acc0 = bias[j], acc1 = acc0;
    const float* wp = Wt + (size_t)j * DD;
    for (int k = 0; k < DD; k += 4) {
        float4 w  = *(const float4*)(wp + k);
        float4 a0 = *(const float4*)(sA + k);
        float4 a1 = *(const float4*)(sA + DD + k);
        acc0 = fmaf(a0.x, w.x, acc0); acc0 = fmaf(a0.y, w.y, acc0);
        acc0 = fmaf(a0.z, w.z, acc0); acc0 = fmaf(a0.w, w.w, acc0);
        acc1 = fmaf(a1.x, w.x, acc1); acc1 = fmaf(a1.y, w.y, acc1);
        acc1 = fmaf(a1.z, w.z, acc1); acc1 = fmaf(a1.w, w.w, acc1);
    }
    float val0 = x[(size_t)r0 * DD + j] + acc0;
    float val1 = x[(size_t)(r0 + 1) * DD + j] + acc1;
    float s0 = val0, q0 = val0 * val0, s1 = val1, q1 = val1 * val1;
    #pragma unroll
    for (int o2 = 32; o2 > 0; o2 >>= 1) {
        s0 += __shfl_xor(s0, o2); q0 += __shfl_xor(q0, o2);
        s1 += __shfl_xor(s1, o2); q1 += __shfl_xor(q1, o2);
    }
    int wid = j >> 6, lane = j & 63;
    if (lane == 0) { redS[wid] = s0; redS2[wid] = q0; redS[4 + wid] = s1; redS2[4 + wid] = q1; }
    __syncthreads();
    if (j < 2) {
        float ts  = redS[j * 4 + 0] + redS[j * 4 + 1] + redS[j * 4 + 2] + redS[j * 4 + 3];
        float ts2 = redS2[j * 4 + 0] + redS2[j * 4 + 1] + redS2[j * 4 + 2] + redS2[j * 4 + 3];
        float mean = ts * (1.f / DD);
        float var = ts2 * (1.f / DD) - mean * mean;
        mu[j] = mean; ri[j] = rsqrtf(var + 1e-5f);
    }
    __syncthreads();
    float g = gam[j], be = bet[j];
    x[(size_t)r0 * DD + j]       = (val0 - mu[0]) * ri[0] * g + be;
    x[(size_t)(r0 + 1) * DD + j] = (val1 - mu[1]) * ri[1] * g + be;
}

// ================= job: sample one row — thread = (view, 8-channel group) =================
template <bool TRANSPOSED>
__device__ __forceinline__ void job_sample(float* sm, int row,
                                           const float* __restrict__ f0,
                                           const float* __restrict__ f1,
                                           const float* __restrict__ f2,
                                           const float* __restrict__ refb,
                                           const float* __restrict__ Rm,
                                           const float* __restrict__ Tm,
                                           const float* __restrict__ Km,
                                           float* __restrict__ fused) {
    float* sg    = sm;           // [8][3]
    float* sPart = sm + 32;      // [8][258]
    int t = threadIdx.x;
    int b = row / NQ;
    if (t < 8) {
        int bv = b * VV + t;
        const float* r = refb + (size_t)row * 3;
        const float* R = Rm + (size_t)bv * 9;
        const float* T = Tm + (size_t)bv * 3;
        const float* K = Km + (size_t)bv * 9;
        float p0 = R[0] * r[0] + R[1] * r[1] + R[2] * r[2] + T[0];
        float p1 = R[3] * r[0] + R[4] * r[1] + R[5] * r[2] + T[1];
        float p2 = R[6] * r[0] + R[7] * r[1] + R[8] * r[2] + T[2];
        float z = fmaxf(p2, 0.1f);
        float u  = p0 * K[0] / z + K[2];
        float vv = p1 * K[4] / z + K[5];
        float un = 2.f * u  / (float)(W_IMG - 1) - 1.f;
        float vn = 2.f * vv / (float)(H_IMG - 1) - 1.f;
        bool m = (un > -1.f) && (un < 1.f) && (vn > -1.f) && (vn < 1.f) && (p2 > 0.f);
        sg[t * 3 + 0] = un; sg[t * 3 + 1] = vn; sg[t * 3 + 2] = m ? 1.f : 0.f;
    }
    __syncthreads();
    int v = t >> 5, cg = t & 31;
    int ch0 = cg * 8;
    float acc[8] = {0, 0, 0, 0, 0, 0, 0, 0};
    float m = sg[v * 3 + 2];
    if (m != 0.f) {
        float un = sg[v * 3 + 0], vn = sg[v * 3 + 1];
        int bv = b * VV + v;
        const float* fl[3] = { f0, f1, f2 };
        const int Hs[3] = { 64, 32, 16 };
        #pragma unroll
        for (int lev = 0; lev < 3; ++lev) {
            int Hh = Hs[lev], Ww = Hs[lev];
            const float* f = fl[lev];
            float xx = (un + 1.f) * Ww * 0.5f - 0.5f;
            float yy = (vn + 1.f) * Hh * 0.5f - 0.5f;
            float x0f = floorf(xx), y0f = floorf(yy);
            int ix0 = (int)x0f, iy0 = (int)y0f;
            float wx1 = xx - x0f, wx0 = 1.f - wx1;
            float wy1 = yy - y0f, wy0 = 1.f - wy1;
            #pragma unroll
            for (int tap = 0; tap < 4; ++tap) {
                int ix = ix0 + (tap & 1);
                int iy = iy0 + (tap >> 1);
                float wgt = ((tap & 1) ? wx1 : wx0) * ((tap >> 1) ? wy1 : wy0);
                if (ix >= 0 && ix < Ww && iy >= 0 && iy < Hh) {
                    if (TRANSPOSED) {
                        const float* p = f + ((size_t)bv * Hh * Ww + (size_t)iy * Ww + ix) * DD + ch0;
                        float4 va = *(const float4*)p;
                        float4 vb = *(const float4*)(p + 4);
                        acc[0] = fmaf(wgt, va.x, acc[0]); acc[1] = fmaf(wgt, va.y, acc[1]);
                        acc[2] = fmaf(wgt, va.z, acc[2]); acc[3] = fmaf(wgt, va.w, acc[3]);
                        acc[4] = fmaf(wgt, vb.x, acc[4]); acc[5] = fmaf(wgt, vb.y, acc[5]);
                        acc[6] = fmaf(wgt, vb.z, acc[6]); acc[7] = fmaf(wgt, vb.w, acc[7]);
                    } else {
                        #pragma unroll
                        for (int c = 0; c < 8; ++c) {
                            float vv2 = f[(((size_t)bv * DD + ch0 + c) * Hh + iy) * Ww + ix];
                            acc[c] = fmaf(wgt, vv2, acc[c]);
                        }
                    }
                }
            }
        }
    }
    #pragma unroll
    for (int c = 0; c < 8; ++c) sPart[v * 258 + ch0 + c] = acc[c] * (1.f / 3.f);
    __syncthreads();
    float cnt = sg[2] + sg[5] + sg[8] + sg[11] + sg[14] + sg[17] + sg[20] + sg[23];
    float s = 0.f;
    #pragma unroll
    for (int v2 = 0; v2 < 8; ++v2) s += sPart[v2 * 258 + t];
    fused[(size_t)row * DD + t] = s / fmaxf(cnt, 1.f);
}

// ================= fused dispatch D: oproj+res+LN (168) + sample (672) =================
template <bool TRANSPOSED>
__global__ __launch_bounds__(256) void oproj_sample(const float* __restrict__ attn_o,
                                                    const float* __restrict__ Wo,
                                                    const float* __restrict__ bo,
                                                    const float* __restrict__ gam,
                                                    const float* __restrict__ bet,
                                                    float* __restrict__ x,
                                                    const float* __restrict__ f0,
                                                    const float* __restrict__ f1,
                                                    const float* __restrict__ f2,
                                                    const float* __restrict__ refb,
                                                    const float* __restrict__ Rm,
                                                    const float* __restrict__ Tm,
                                                    const float* __restrict__ Km,
                                                    float* __restrict__ fused) {
    __shared__ float sm[2112];
    if (blockIdx.x < 168)
        job_gemm_ln(sm, blockIdx.x * 4, attn_o, Wo, bo, gam, bet, x);
    else
        job_sample<TRANSPOSED>(sm, blockIdx.x - 168, f0, f1, f2, refb, Rm, Tm, Km, fused);
}

// ================= generic tiled GEMM. MODE 0 plain, 1 relu. grid (21, N/64, KS) =================
template <int MODE>
__global__ __launch_bounds__(256) void gemm_tile(const float* __restrict__ A,
                                                 const float* __restrict__ W,
                                                 const float* __restrict__ bias,
                                                 float* __restrict__ C,
                                                 int Ktot, int Kper, int Nout) {
    __shared__ float At[32][34];
    __shared__ float Wt[32][68];
    int t = threadIdx.x;
    int m0 = blockIdx.x * 32;
    int n0 = blockIdx.y * 64;
    int kz = blockIdx.z;
    int kofs = kz * Kper;
    int tx = t & 15, ty = t >> 4;
    int nc = n0 + tx * 4;
    float acc0[4], acc1[4];
    {
        float4 bv = make_float4(0.f, 0.f, 0.f, 0.f);
        if (bias && kz == 0) bv = *(const float4*)(bias + nc);
        acc0[0] = bv.x; acc0[1] = bv.y; acc0[2] = bv.z; acc0[3] = bv.w;
        acc1[0] = bv.x; acc1[1] = bv.y; acc1[2] = bv.z; acc1[3] = bv.w;
    }
    int am = t >> 3, ak4 = (t & 7) * 4;
    int ktiles = Kper >> 5;
    for (int kt = 0; kt < ktiles; ++kt) {
        int kk = kofs + kt * 32;
        __syncthreads();
        {
            float4 v = *(const float4*)(A + (size_t)(m0 + am) * Ktot + kk + ak4);
            At[ak4 + 0][am] = v.x; At[ak4 + 1][am] = v.y;
            At[ak4 + 2][am] = v.z; At[ak4 + 3][am] = v.w;
        }
        #pragma unroll
        for (int s = 0; s < 2; ++s) {
            int idx = t + s * 256;
            int wn = idx >> 3, wk4 = (idx & 7) * 4;
            float4 v = *(const float4*)(W + (size_t)(n0 + wn) * Ktot + kk + wk4);
            Wt[wk4 + 0][wn] = v.x; Wt[wk4 + 1][wn] = v.y;
            Wt[wk4 + 2][wn] = v.z; Wt[wk4 + 3][wn] = v.w;
        }
        __syncthreads();
        #pragma unroll
        for (int k = 0; k < 32; ++k) {
            float2 av = *(const float2*)&At[k][ty * 2];
            float4 wv = *(const float4*)&Wt[k][tx * 4];
            acc0[0] = fmaf(av.x, wv.x, acc0[0]); acc0[1] = fmaf(av.x, wv.y, acc0[1]);
            acc0[2] = fmaf(av.x, wv.z, acc0[2]); acc0[3] = fmaf(av.x, wv.w, acc0[3]);
            acc1[0] = fmaf(av.y, wv.x, acc1[0]); acc1[1] = fmaf(av.y, wv.y, acc1[1]);
            acc1[2] = fmaf(av.y, wv.z, acc1[2]); acc1[3] = fmaf(av.y, wv.w, acc1[3]);
        }
    }
    if (MODE == 1) {
        #pragma unroll
        for (int j = 0; j < 4; ++j) { acc0[j] = fmaxf(acc0[j], 0.f); acc1[j] = fmaxf(acc1[j], 0.f); }
    }
    int mr = m0 + ty * 2;
    float* Cb = C + (size_t)kz * MROWS * Nout;
    *(float4*)(Cb + (size_t)mr * Nout + nc)       = make_float4(acc0[0], acc0[1], acc0[2], acc0[3]);
    *(float4*)(Cb + (size_t)(mr + 1) * Nout + nc) = make_float4(acc1[0], acc1[1], acc1[2], acc1[3]);
}

// ================= residual + LN over NP k-split partials; xq = out + qp =================
template <int NP>
__global__ __launch_bounds__(256) void ln_res(float* __restrict__ x,
                                              const float* __restrict__ C,
                                              const float* __restrict__ gam,
                                              const float* __restrict__ bet,
                                              const float* __restrict__ qp,
                                              float* __restrict__ xq) {
    __shared__ float redS[4][4], redS2[4][4];
    __shared__ float mu[4], ri[4];
    int r0 = blockIdx.x * 4;
    int j = threadIdx.x;
    float val[4];
    #pragma unroll
    for (int r = 0; r < 4; ++r) {
        float a = x[(size_t)(r0 + r) * DD + j];
        #pragma unroll
        for (int p = 0; p < NP; ++p) a += C[(size_t)p * MROWS * DD + (size_t)(r0 + r) * DD + j];
        val[r] = a;
    }
    float s[4], s2[4];
    #pragma unroll
    for (int r = 0; r < 4; ++r) { s[r] = val[r]; s2[r] = val[r] * val[r]; }
    #pragma unroll
    for (int o = 32; o > 0; o >>= 1) {
        #pragma unroll
        for (int r = 0; r < 4; ++r) {
            s[r]  += __shfl_xor(s[r],  o);
            s2[r] += __shfl_xor(s2[r], o);
        }
    }
    int wid = j >> 6, lane = j & 63;
    if (lane == 0) {
        #pragma unroll
        for (int r = 0; r < 4; ++r) { redS[r][wid] = s[r]; redS2[r][wid] = s2[r]; }
    }
    __syncthreads();
    if (j < 4) {
        int r = j;
        float ts  = redS[r][0]  + redS[r][1]  + redS[r][2]  + redS[r][3];
        float ts2 = redS2[r][0] + redS2[r][1] + redS2[r][2] + redS2[r][3];
        float mean = ts * (1.f / DD);
        float var = ts2 * (1.f / DD) - mean * mean;
        mu[r] = mean;
        ri[r] = rsqrtf(var + 1e-5f);
    }
    __syncthreads();
    float g = gam[j], be = bet[j];
    #pragma unroll
    for (int r = 0; r < 4; ++r) {
        float o = (val[r] - mu[r]) * ri[r] * g + be;
        x[(size_t)(r0 + r) * DD + j] = o;
        if (qp) xq[(size_t)(r0 + r) * DD + j] = o + qp[(size_t)(r0 + r) * DD + j];
    }
}

extern "C" void kernel_launch(void* const* d_in, const int* in_sizes, int n_in,
                              void* d_out, int out_size, void* d_ws, size_t ws_size,
                              hipStream_t stream) {
    const float* tgt       = (const float*)d_in[0];
    const float* query_pos = (const float*)d_in[1];
    const float* refpts    = (const float*)d_in[2];
    const float* feat0     = (const float*)d_in[3];
    const float* feat1     = (const float*)d_in[4];
    const float* feat2     = (const float*)d_in[5];
    const float* camR      = (const float*)d_in[6];
    const float* camT      = (const float*)d_in[7];
    const float* camK      = (const float*)d_in[8];
    const float* Wqkv      = (const float*)d_in[9];
    const float* bqkv      = (const float*)d_in[10];
    const float* Wo        = (const float*)d_in[11];
    const float* bo        = (const float*)d_in[12];
    const float* ln1_g     = (const float*)d_in[13];
    const float* ln1_b     = (const float*)d_in[14];
    const float* Wproj     = (const float*)d_in[15];
    const float* bproj     = (const float*)d_in[16];
    const float* pn_g      = (const float*)d_in[17];
    const float* pn_b      = (const float*)d_in[18];
    const float* W1        = (const float*)d_in[19];
    const float* b1        = (const float*)d_in[20];
    const float* W2        = (const float*)d_in[21];
    const float* b2        = (const float*)d_in[22];
    const float* ln2_g     = (const float*)d_in[23];
    const float* ln2_b     = (const float*)d_in[24];
    const float* pose_W0   = (const float*)d_in[25];
    const float* pose_b0   = (const float*)d_in[26];
    const float* pose_W1   = (const float*)d_in[27];
    const float* pose_b1   = (const float*)d_in[28];
    const float* pose_W2   = (const float*)d_in[29];
    const float* pose_b2   = (const float*)d_in[30];
    const float* cls_W     = (const float*)d_in[31];
    const float* cls_b     = (const float*)d_in[32];
    float* out = (float*)d_out;

    float* w = (float*)d_ws;
    size_t off = 0;
    auto alloc = [&](size_t n) { float* p = w + off; off += n; return p; };
    float* x      = alloc((size_t)BQ * DD);
    float* xq     = alloc((size_t)BQ * DD);
    float* Qp     = alloc((size_t)BB * HEADS * NQ * HD);
    float* Kp     = alloc((size_t)BB * HEADS * NQ * HD);
    float* Vp     = alloc((size_t)BB * HEADS * NQ * HD);
    float* attn_o = alloc((size_t)BQ * DD);
    float* fused  = alloc((size_t)BQ * DD);
    float* ffh    = alloc((size_t)BQ * FF);
    float* ctmp   = alloc((size_t)4 * BQ * DD);
    float* refb   = alloc((size_t)BQ * 3 + 64);
    size_t base_floats = off;
    size_t featT_floats = (size_t)BB * VV * DD * (64 * 64 + 32 * 32 + 16 * 16);
    bool useT = ws_size >= (base_floats + featT_floats) * sizeof(float);
    float *fT0 = nullptr, *fT1 = nullptr, *fT2 = nullptr;
    if (useT) {
        fT0 = alloc((size_t)BB * VV * 64 * 64 * DD);
        fT1 = alloc((size_t)BB * VV * 32 * 32 * DD);
        fT2 = alloc((size_t)BB * VV * 16 * 16 * DD);
    }

    // init x, xq, refb (168 blocks). Separate dispatch: layer-0 qkv reads xq.
    init_k<<<168, 256, 0, stream>>>(tgt, query_pos, refpts, x, xq, refb);

    for (int l = 0; l < NL; ++l) {
        // A: qkv (252) + [l==0: full feature transpose (5376)] / [l>0: pose head (168)]
        if (l == 0 && useT) {
            qkv_tr<<<252 + 5376, 256, 0, stream>>>(
                xq, x, Wqkv, bqkv, Qp, Kp, Vp,
                feat0, feat1, feat2, fT0, fT1, fT2);
        } else {
            qkv_pose<<<252 + (l > 0 ? 168 : 0), 256, 0, stream>>>(
                xq, x, Wqkv + (size_t)l * 3 * DD * DD, bqkv + (size_t)l * 3 * DD, Qp, Kp, Vp,
                pose_W0, pose_b0, pose_W1, pose_b1, pose_W2, pose_b2, cls_W, cls_b,
                refb, out + (size_t)(l - 1) * BQ * 4);
        }
        // B: fused attention (176 blocks, pure)
        attn_fused<<<176, 256, 0, stream>>>(Qp, Kp, Vp, attn_o);
        // D: oproj+res+LN1 (168) + sample (672)
        if (useT)
            oproj_sample<true><<<840, 256, 0, stream>>>(
                attn_o, Wo + (size_t)l * DD * DD, bo + (size_t)l * DD,
                ln1_g + (size_t)l * DD, ln1_b + (size_t)l * DD, x,
                fT0, fT1, fT2, refb, camR, camT, camK, fused);
        else
            oproj_sample<false><<<840, 256, 0, stream>>>(
                attn_o, Wo + (size_t)l * DD * DD, bo + (size_t)l * DD,
                ln1_g + (size_t)l * DD, ln1_b + (size_t)l * DD, x,
                feat0, feat1, feat2, refb, camR, camT, camK, fused);
        // E: proj-GEMM + res + LNpn (2 rows x 336 blocks: 2x TLP vs 168-block 4-row)
        gemm2_res_ln<<<BQ / 2, 256, 0, stream>>>(
            fused, Wproj + (size_t)l * DD * DD, bproj + (size_t)l * DD,
            pn_g + (size_t)l * DD, pn_b + (size_t)l * DD, x);
        // FFN1 (relu)
        gemm_tile<1><<<dim3(21, 16, 1), 256, 0, stream>>>(
            x, W1 + (size_t)l * FF * DD, b1 + (size_t)l * FF, ffh, DD, DD, FF);
        // FFN2 k-split (336 blocks) + ln_res (168): occupancy beats fusion here (r2).
        gemm_tile<0><<<dim3(21, 4, 4), 256, 0, stream>>>(
            ffh, W2 + (size_t)l * DD * FF, b2 + (size_t)l * DD, ctmp, FF, FF / 4, DD);
        ln_res<4><<<BQ / 4, 256, 0, stream>>>(
            x, ctmp, ln2_g + (size_t)l * DD, ln2_b + (size_t)l * DD, query_pos, xq);
    }
    // tail: pose head of layer NL-1
    pose_only<<<BQ / 4, 256, 0, stream>>>(
        x, pose_W0, pose_b0, pose_W1, pose_b1, pose_W2, pose_b2, cls_W, cls_b,
        refb, out + (size_t)(NL - 1) * BQ * 4);
}

// Round 7
// 842.269 us; speedup vs baseline: 1.1004x; 1.0198x over previous
//
#include <hip/hip_runtime.h>
#include <math.h>

#define BB 2
#define VV 8
#define NQ 336
#define DD 256
#define HEADS 8
#define HD 32
#define FF 1024
#define NL 6
#define BQ (BB*NQ)
#define W_IMG 512
#define H_IMG 512
#define MROWS BQ

// ================= job: 128ch x 32px transpose tile (5376 tiles) =================
// 16.9 KB LDS -> 8 blocks/CU (wave-capped). 512B-contiguous channel writes.
// At ~7.7 TB/s combined fabric throughput (r3 counters) — memory-system-limited.
__device__ __forceinline__ void job_transpose3(float* tile, int b,
                                               const float* __restrict__ f0,
                                               const float* __restrict__ f1,
                                               const float* __restrict__ f2,
                                               float* __restrict__ o0,
                                               float* __restrict__ o1,
                                               float* __restrict__ o2) {
    const float* src; float* dst; int HW, ptiles;
    if (b < 4096)      { src = f0; dst = o0; HW = 4096; ptiles = 128; }
    else if (b < 5120) { b -= 4096; src = f1; dst = o1; HW = 1024; ptiles = 32; }
    else               { b -= 5120; src = f2; dst = o2; HW = 256;  ptiles = 8;  }
    int cg = b & 1;
    int pt = (b >> 1) % ptiles;
    int bv = (b >> 1) / ptiles;
    int d0 = cg * 128, p0 = pt * 32;
    int t = threadIdx.x;
    int chb = t >> 3, px4 = (t & 7) * 4;
    #pragma unroll
    for (int pass = 0; pass < 4; ++pass) {
        int ch = pass * 32 + chb;
        float4 v = *(const float4*)(src + ((size_t)(bv * DD + d0 + ch)) * HW + p0 + px4);
        tile[ch * 33 + px4 + 0] = v.x; tile[ch * 33 + px4 + 1] = v.y;
        tile[ch * 33 + px4 + 2] = v.z; tile[ch * 33 + px4 + 3] = v.w;
    }
    __syncthreads();
    int c4 = (t & 31) * 4, pxb = t >> 5;
    #pragma unroll
    for (int pass = 0; pass < 4; ++pass) {
        int px = pass * 8 + pxb;
        float4 o;
        o.x = tile[(c4 + 0) * 33 + px];
        o.y = tile[(c4 + 1) * 33 + px];
        o.z = tile[(c4 + 2) * 33 + px];
        o.w = tile[(c4 + 3) * 33 + px];
        *(float4*)(dst + ((size_t)bv * HW + p0 + px) * DD + d0 + c4) = o;
    }
}

// ================= init (168 blocks) =================
__global__ __launch_bounds__(256) void init_k(const float* __restrict__ tgt,
                                              const float* __restrict__ qp,
                                              const float* __restrict__ refpts,
                                              float* __restrict__ x,
                                              float* __restrict__ xq,
                                              float* __restrict__ refb) {
    int i = blockIdx.x * 256 + threadIdx.x;
    float4 tv = ((const float4*)tgt)[i];
    float4 qv = ((const float4*)qp)[i];
    ((float4*)x)[i] = tv;
    ((float4*)xq)[i] = make_float4(tv.x + qv.x, tv.y + qv.y, tv.z + qv.z, tv.w + qv.w);
    if (i < BQ * 3) refb[i] = refpts[i];
}

// ================= job: 32x64 qkv tile, head-packed output =================
__device__ __forceinline__ void job_qkv(float* sm, int bid,
                                        const float* __restrict__ Aq,
                                        const float* __restrict__ Ax,
                                        const float* __restrict__ W,
                                        const float* __restrict__ bias,
                                        float* __restrict__ Qp,
                                        float* __restrict__ Kp,
                                        float* __restrict__ Vp) {
    float* At = sm;            // [32][34]
    float* Wt = sm + 1088;     // [32][68]
    int t = threadIdx.x;
    int m0 = (bid % 21) * 32;
    int ncol = bid / 21;
    int n0 = ncol * 64;
    const float* A = (ncol < 8) ? Aq : Ax;
    int tx = t & 15, ty = t >> 4;
    int nc = n0 + tx * 4;
    float acc0[4], acc1[4];
    {
        float4 bv = *(const float4*)(bias + nc);
        acc0[0] = bv.x; acc0[1] = bv.y; acc0[2] = bv.z; acc0[3] = bv.w;
        acc1[0] = bv.x; acc1[1] = bv.y; acc1[2] = bv.z; acc1[3] = bv.w;
    }
    int am = t >> 3, ak4 = (t & 7) * 4;
    for (int kt = 0; kt < 8; ++kt) {
        int kk = kt * 32;
        __syncthreads();
        {
            float4 v = *(const float4*)(A + (size_t)(m0 + am) * DD + kk + ak4);
            At[(ak4 + 0) * 34 + am] = v.x; At[(ak4 + 1) * 34 + am] = v.y;
            At[(ak4 + 2) * 34 + am] = v.z; At[(ak4 + 3) * 34 + am] = v.w;
        }
        #pragma unroll
        for (int s = 0; s < 2; ++s) {
            int idx = t + s * 256;
            int wn = idx >> 3, wk4 = (idx & 7) * 4;
            float4 v = *(const float4*)(W + (size_t)(n0 + wn) * DD + kk + wk4);
            Wt[(wk4 + 0) * 68 + wn] = v.x; Wt[(wk4 + 1) * 68 + wn] = v.y;
            Wt[(wk4 + 2) * 68 + wn] = v.z; Wt[(wk4 + 3) * 68 + wn] = v.w;
        }
        __syncthreads();
        #pragma unroll
        for (int k = 0; k < 32; ++k) {
            float2 av = *(const float2*)&At[k * 34 + ty * 2];
            float4 wv = *(const float4*)&Wt[k * 68 + tx * 4];
            acc0[0] = fmaf(av.x, wv.x, acc0[0]); acc0[1] = fmaf(av.x, wv.y, acc0[1]);
            acc0[2] = fmaf(av.x, wv.z, acc0[2]); acc0[3] = fmaf(av.x, wv.w, acc0[3]);
            acc1[0] = fmaf(av.y, wv.x, acc1[0]); acc1[1] = fmaf(av.y, wv.y, acc1[1]);
            acc1[2] = fmaf(av.y, wv.z, acc1[2]); acc1[3] = fmaf(av.y, wv.w, acc1[3]);
        }
    }
    int mr = m0 + ty * 2;
    int kind = nc >> 8;
    float* base = kind == 0 ? Qp : (kind == 1 ? Kp : Vp);
    int h = (nc >> 5) & 7, d4 = nc & 31;
    #pragma unroll
    for (int i = 0; i < 2; ++i) {
        int m = mr + i;
        int b = m / NQ, q = m - b * NQ;
        float* p = base + ((size_t)((b << 3) + h) * NQ + q) * HD + d4;
        float* src = i == 0 ? acc0 : acc1;
        *(float4*)p = make_float4(src[0], src[1], src[2], src[3]);
    }
}

// ================= job: pose MLP + heads for 4 rows =================
__device__ __forceinline__ void job_pose(float* sm, int job,
                                         const float* __restrict__ x,
                                         const float* __restrict__ W0, const float* __restrict__ b0,
                                         const float* __restrict__ W1p, const float* __restrict__ b1p,
                                         const float* __restrict__ W2p, const float* __restrict__ b2p,
                                         const float* __restrict__ cW, const float* __restrict__ cb,
                                         float* __restrict__ refb, float* __restrict__ outp) {
    float* sX  = sm;          // 1024
    float* sH  = sm + 1024;   // 1024
    float* red = sm + 2048;   // 64
    int r0 = job * 4;
    int tid = threadIdx.x;
    ((float4*)sX)[tid] = ((const float4*)(x + (size_t)r0 * DD))[tid];
    __syncthreads();
    {
        float a0 = b0[tid], a1 = a0, a2 = a0, a3 = a0;
        const float* wp = W0 + (size_t)tid * DD;
        for (int k = 0; k < DD; k += 4) {
            float4 w  = *(const float4*)(wp + k);
            float4 x0 = *(const float4*)(sX + 0 * DD + k);
            float4 x1 = *(const float4*)(sX + 1 * DD + k);
            float4 x2 = *(const float4*)(sX + 2 * DD + k);
            float4 x3 = *(const float4*)(sX + 3 * DD + k);
            a0 = fmaf(x0.x, w.x, a0); a0 = fmaf(x0.y, w.y, a0); a0 = fmaf(x0.z, w.z, a0); a0 = fmaf(x0.w, w.w, a0);
            a1 = fmaf(x1.x, w.x, a1); a1 = fmaf(x1.y, w.y, a1); a1 = fmaf(x1.z, w.z, a1); a1 = fmaf(x1.w, w.w, a1);
            a2 = fmaf(x2.x, w.x, a2); a2 = fmaf(x2.y, w.y, a2); a2 = fmaf(x2.z, w.z, a2); a2 = fmaf(x2.w, w.w, a2);
            a3 = fmaf(x3.x, w.x, a3); a3 = fmaf(x3.y, w.y, a3); a3 = fmaf(x3.z, w.z, a3); a3 = fmaf(x3.w, w.w, a3);
        }
        sH[0 * DD + tid] = fmaxf(a0, 0.f);
        sH[1 * DD + tid] = fmaxf(a1, 0.f);
        sH[2 * DD + tid] = fmaxf(a2, 0.f);
        sH[3 * DD + tid] = fmaxf(a3, 0.f);
    }
    __syncthreads();
    float h[4];
    {
        float a0 = b1p[tid], a1 = a0, a2 = a0, a3 = a0;
        const float* wp = W1p + (size_t)tid * DD;
        for (int k = 0; k < DD; k += 4) {
            float4 w  = *(const float4*)(wp + k);
            float4 x0 = *(const float4*)(sH + 0 * DD + k);
            float4 x1 = *(const float4*)(sH + 1 * DD + k);
            float4 x2 = *(const float4*)(sH + 2 * DD + k);
            float4 x3 = *(const float4*)(sH + 3 * DD + k);
            a0 = fmaf(x0.x, w.x, a0); a0 = fmaf(x0.y, w.y, a0); a0 = fmaf(x0.z, w.z, a0); a0 = fmaf(x0.w, w.w, a0);
            a1 = fmaf(x1.x, w.x, a1); a1 = fmaf(x1.y, w.y, a1); a1 = fmaf(x1.z, w.z, a1); a1 = fmaf(x1.w, w.w, a1);
            a2 = fmaf(x2.x, w.x, a2); a2 = fmaf(x2.y, w.y, a2); a2 = fmaf(x2.z, w.z, a2); a2 = fmaf(x2.w, w.w, a2);
            a3 = fmaf(x3.x, w.x, a3); a3 = fmaf(x3.y, w.y, a3); a3 = fmaf(x3.z, w.z, a3); a3 = fmaf(x3.w, w.w, a3);
        }
        h[0] = fmaxf(a0, 0.f); h[1] = fmaxf(a1, 0.f); h[2] = fmaxf(a2, 0.f); h[3] = fmaxf(a3, 0.f);
    }
    float w2a = W2p[tid], w2b = W2p[DD + tid], w2c = W2p[2 * DD + tid], cw = cW[tid];
    float v[4][4];
    #pragma unroll
    for (int r = 0; r < 4; ++r) {
        v[r][0] = h[r] * w2a;
        v[r][1] = h[r] * w2b;
        v[r][2] = h[r] * w2c;
        v[r][3] = sX[r * DD + tid] * cw;
    }
    #pragma unroll
    for (int o2 = 32; o2 > 0; o2 >>= 1) {
        #pragma unroll
        for (int r = 0; r < 4; ++r) {
            #pragma unroll
            for (int c = 0; c < 4; ++c) v[r][c] += __shfl_xor(v[r][c], o2);
        }
    }
    int wid = tid >> 6, lane = tid & 63;
    if (lane == 0) {
        #pragma unroll
        for (int r = 0; r < 4; ++r) {
            #pragma unroll
            for (int c = 0; c < 4; ++c) red[(r * 4 + c) * 4 + wid] = v[r][c];
        }
    }
    __syncthreads();
    if (tid < 4) {
        int r = tid;
        float d0 = red[(r * 4 + 0) * 4 + 0] + red[(r * 4 + 0) * 4 + 1] + red[(r * 4 + 0) * 4 + 2] + red[(r * 4 + 0) * 4 + 3] + b2p[0];
        float d1 = red[(r * 4 + 1) * 4 + 0] + red[(r * 4 + 1) * 4 + 1] + red[(r * 4 + 1) * 4 + 2] + red[(r * 4 + 1) * 4 + 3] + b2p[1];
        float d2 = red[(r * 4 + 2) * 4 + 0] + red[(r * 4 + 2) * 4 + 1] + red[(r * 4 + 2) * 4 + 2] + red[(r * 4 + 2) * 4 + 3] + b2p[2];
        float cl = red[(r * 4 + 3) * 4 + 0] + red[(r * 4 + 3) * 4 + 1] + red[(r * 4 + 3) * 4 + 2] + red[(r * 4 + 3) * 4 + 3] + cb[0];
        int row = r0 + r;
        float rx = refb[(size_t)row * 3 + 0] + d0;
        float ry = refb[(size_t)row * 3 + 1] + d1;
        float rz = refb[(size_t)row * 3 + 2] + d2;
        refb[(size_t)row * 3 + 0] = rx;
        refb[(size_t)row * 3 + 1] = ry;
        refb[(size_t)row * 3 + 2] = rz;
        outp[(size_t)row * 4 + 0] = cl;
        outp[(size_t)row * 4 + 1] = rx;
        outp[(size_t)row * 4 + 2] = ry;
        outp[(size_t)row * 4 + 3] = rz;
    }
}

// ================= fused dispatch A: qkv (252) + pose of prev layer (168) =================
__global__ __launch_bounds__(256) void qkv_pose(const float* __restrict__ xq,
                                                const float* __restrict__ x,
                                                const float* __restrict__ Wqkv,
                                                const float* __restrict__ bqkv,
                                                float* __restrict__ Qp,
                                                float* __restrict__ Kp,
                                                float* __restrict__ Vp,
                                                const float* __restrict__ pW0, const float* __restrict__ pb0,
                                                const float* __restrict__ pW1, const float* __restrict__ pb1,
                                                const float* __restrict__ pW2, const float* __restrict__ pb2,
                                                const float* __restrict__ cW, const float* __restrict__ cb,
                                                float* __restrict__ refb, float* __restrict__ outp) {
    __shared__ float sm[3264];
    if (blockIdx.x < 252)
        job_qkv(sm, blockIdx.x, xq, x, Wqkv, bqkv, Qp, Kp, Vp);
    else
        job_pose(sm, blockIdx.x - 252, x, pW0, pb0, pW1, pb1, pW2, pb2, cW, cb, refb, outp);
}

// ================= layer-0 variant: qkv (252) + full transpose (5376) =================
__global__ __launch_bounds__(256) void qkv_tr(const float* __restrict__ xq,
                                              const float* __restrict__ x,
                                              const float* __restrict__ Wqkv,
                                              const float* __restrict__ bqkv,
                                              float* __restrict__ Qp,
                                              float* __restrict__ Kp,
                                              float* __restrict__ Vp,
                                              const float* __restrict__ f0,
                                              const float* __restrict__ f1,
                                              const float* __restrict__ f2,
                                              float* __restrict__ o0,
                                              float* __restrict__ o1,
                                              float* __restrict__ o2) {
    __shared__ float sm[4224];
    if (blockIdx.x < 252)
        job_qkv(sm, blockIdx.x, xq, x, Wqkv, bqkv, Qp, Kp, Vp);
    else
        job_transpose3(sm, blockIdx.x - 252, f0, f1, f2, o0, o1, o2);
}

// standalone pose (tail)
__global__ __launch_bounds__(256) void pose_only(const float* __restrict__ x,
                                                 const float* __restrict__ pW0, const float* __restrict__ pb0,
                                                 const float* __restrict__ pW1, const float* __restrict__ pb1,
                                                 const float* __restrict__ pW2, const float* __restrict__ pb2,
                                                 const float* __restrict__ cW, const float* __restrict__ cb,
                                                 float* __restrict__ refb, float* __restrict__ outp) {
    __shared__ float sm[2112];
    job_pose(sm, blockIdx.x, x, pW0, pb0, pW1, pb1, pW2, pb2, cW, cb, refb, outp);
}

// ================= 16-row fused attention (scores + exact softmax + PV in LDS) =================
// 352 blocks (16 bh x 22 q-tiles), 39 KB LDS -> 1.4 blocks/CU by count, 4/CU by LDS.
// Replaces the 176-block 61 KB version (0.69 blocks/CU): 2x resident parallelism.
// Functionally verified in round 4 (passed).
__global__ __launch_bounds__(256) void attn16(const float* __restrict__ Qp,
                                              const float* __restrict__ Kp,
                                              const float* __restrict__ Vp,
                                              float* __restrict__ O) {
    __shared__ float sm[9744];
    float* S   = sm;            // [16][344]  5504
    float* KT  = sm + 5504;     // [32][68]   2176
    float* U   = sm + 7680;     // union: QT [32][20]=640 / Vt [64][32]=2048
    float* inv = sm + 9728;     // [16]
    int blk = blockIdx.x;
    int bh = blk & 15, qt = blk >> 4;   // qt 0..21
    int t = threadIdx.x;
    const float scale = 0.17677669529663687f;
    const float* Qb = Qp + (size_t)bh * NQ * HD;
    const float* Kb = Kp + (size_t)bh * NQ * HD;
    const float* Vb = Vp + (size_t)bh * NQ * HD;
    // stage Q^T scaled: QT[d][q], 16 rows
    if (t < 128) {
        int ql = t >> 3, d4 = (t & 7) * 4;
        int qg = qt * 16 + ql;
        float4 v = (qg < NQ) ? *(const float4*)(Qb + (size_t)qg * HD + d4)
                             : make_float4(0.f, 0.f, 0.f, 0.f);
        U[(d4 + 0) * 20 + ql] = v.x * scale;
        U[(d4 + 1) * 20 + ql] = v.y * scale;
        U[(d4 + 2) * 20 + ql] = v.z * scale;
        U[(d4 + 3) * 20 + ql] = v.w * scale;
    }
    int r = t >> 4, tx = t & 15;
    for (int kt = 0; kt < 6; ++kt) {
        __syncthreads();
        #pragma unroll
        for (int s = 0; s < 2; ++s) {
            int idx = t + s * 256;
            int kl = idx >> 3, d4 = (idx & 7) * 4;
            int kg = kt * 64 + kl;
            float4 v = (kg < NQ) ? *(const float4*)(Kb + (size_t)kg * HD + d4)
                                 : make_float4(0.f, 0.f, 0.f, 0.f);
            KT[(d4 + 0) * 68 + kl] = v.x; KT[(d4 + 1) * 68 + kl] = v.y;
            KT[(d4 + 2) * 68 + kl] = v.z; KT[(d4 + 3) * 68 + kl] = v.w;
        }
        __syncthreads();
        float a0 = 0.f, a1 = 0.f, a2 = 0.f, a3 = 0.f;
        #pragma unroll
        for (int k = 0; k < 32; ++k) {
            float qv = U[k * 20 + r];
            float4 kv = *(const float4*)&KT[k * 68 + tx * 4];
            a0 = fmaf(qv, kv.x, a0); a1 = fmaf(qv, kv.y, a1);
            a2 = fmaf(qv, kv.z, a2); a3 = fmaf(qv, kv.w, a3);
        }
        int col = kt * 64 + tx * 4;
        if (col < NQ)
            *(float4*)&S[r * 344 + col] = make_float4(a0, a1, a2, a3);
    }
    __syncthreads();
    // exact 2-pass softmax over 336 cols (16 lanes/row, 21 strided each)
    {
        float* row = S + (size_t)r * 344;
        float m = -1e30f;
        for (int i = 0; i < 21; ++i) m = fmaxf(m, row[tx + 16 * i]);
        m = fmaxf(m, __shfl_xor(m, 1));
        m = fmaxf(m, __shfl_xor(m, 2));
        m = fmaxf(m, __shfl_xor(m, 4));
        m = fmaxf(m, __shfl_xor(m, 8));
        float ssum = 0.f;
        for (int i = 0; i < 21; ++i) {
            float e = expf(row[tx + 16 * i] - m);
            row[tx + 16 * i] = e;
            ssum += e;
        }
        ssum += __shfl_xor(ssum, 1);
        ssum += __shfl_xor(ssum, 2);
        ssum += __shfl_xor(ssum, 4);
        ssum += __shfl_xor(ssum, 8);
        if (tx == 0) inv[r] = 1.f / ssum;
    }
    // PV: thread = (q row r, 2 d cols)
    int d0 = tx * 2;
    float acc0 = 0.f, acc1 = 0.f;
    for (int kt = 0; kt < 6; ++kt) {
        __syncthreads();
        #pragma unroll
        for (int s = 0; s < 2; ++s) {
            int idx = t + s * 256;
            int kl = idx >> 3, d4 = (idx & 7) * 4;
            int kg = kt * 64 + kl;
            float4 v = (kg < NQ) ? *(const float4*)(Vb + (size_t)kg * HD + d4)
                                 : make_float4(0.f, 0.f, 0.f, 0.f);
            *(float4*)&U[kl * 32 + d4] = v;   // Vt
        }
        __syncthreads();
        int kmax = (kt == 5) ? 16 : 64;       // keys 320..335 only (NQ=336)
        const float* Srow = S + (size_t)r * 344 + kt * 64;
        #pragma unroll 8
        for (int kk = 0; kk < kmax; ++kk) {
            float p = Srow[kk];
            float2 vv = *(const float2*)&U[kk * 32 + d0];
            acc0 = fmaf(p, vv.x, acc0); acc1 = fmaf(p, vv.y, acc1);
        }
    }
    float iv = inv[r];
    int qg = qt * 16 + r;
    int b = bh >> 3, h = bh & 7;
    if (qg < NQ)
        *(float2*)(O + ((size_t)(b * NQ + qg)) * DD + h * HD + d0) =
            make_float2(acc0 * iv, acc1 * iv);
}

// ================= job: row-block GEMM(K=256,N=256) + residual + LN (4 rows) =================
__device__ __forceinline__ void job_gemm_ln(float* sm, int r0,
                                            const float* __restrict__ A,
                                            const float* __restrict__ Wt,
                                            const float* __restrict__ bias,
                                            const float* __restrict__ gam,
                                            const float* __restrict__ bet,
                                            float* __restrict__ x) {
    float* sA    = sm;          // 1024
    float* redS  = sm + 1024;   // 16
    float* redS2 = sm + 1040;   // 16
    float* mu    = sm + 1056;   // 4
    float* ri    = sm + 1060;   // 4
    int j = threadIdx.x;
    ((float4*)sA)[j] = ((const float4*)(A + (size_t)r0 * DD))[j];
    __syncthreads();
    float acc0 = bias[j], acc1 = acc0, acc2 = acc0, acc3 = acc0;
    const float* wp = Wt + (size_t)j * DD;
    for (int k = 0; k < DD; k += 4) {
        float4 w  = *(const float4*)(wp + k);
        float4 a0 = *(const float4*)(sA + 0 * DD + k);
        float4 a1 = *(const float4*)(sA + 1 * DD + k);
        float4 a2 = *(const float4*)(sA + 2 * DD + k);
        float4 a3 = *(const float4*)(sA + 3 * DD + k);
        acc0 = fmaf(a0.x, w.x, acc0); acc0 = fmaf(a0.y, w.y, acc0); acc0 = fmaf(a0.z, w.z, acc0); acc0 = fmaf(a0.w, w.w, acc0);
        acc1 = fmaf(a1.x, w.x, acc1); acc1 = fmaf(a1.y, w.y, acc1); acc1 = fmaf(a1.z, w.z, acc1); acc1 = fmaf(a1.w, w.w, acc1);
        acc2 = fmaf(a2.x, w.x, acc2); acc2 = fmaf(a2.y, w.y, acc2); acc2 = fmaf(a2.z, w.z, acc2); acc2 = fmaf(a2.w, w.w, acc2);
        acc3 = fmaf(a3.x, w.x, acc3); acc3 = fmaf(a3.y, w.y, acc3); acc3 = fmaf(a3.z, w.z, acc3); acc3 = fmaf(a3.w, w.w, acc3);
    }
    float val[4];
    val[0] = x[(size_t)(r0 + 0) * DD + j] + acc0;
    val[1] = x[(size_t)(r0 + 1) * DD + j] + acc1;
    val[2] = x[(size_t)(r0 + 2) * DD + j] + acc2;
    val[3] = x[(size_t)(r0 + 3) * DD + j] + acc3;
    float s[4], s2[4];
    #pragma unroll
    for (int r = 0; r < 4; ++r) { s[r] = val[r]; s2[r] = val[r] * val[r]; }
    #pragma unroll
    for (int o2 = 32; o2 > 0; o2 >>= 1) {
        #pragma unroll
        for (int r = 0; r < 4; ++r) {
            s[r]  += __shfl_xor(s[r],  o2);
            s2[r] += __shfl_xor(s2[r], o2);
        }
    }
    int wid = j >> 6, lane = j & 63;
    if (lane == 0) {
        #pragma unroll
        for (int r = 0; r < 4; ++r) { redS[r * 4 + wid] = s[r]; redS2[r * 4 + wid] = s2[r]; }
    }
    __syncthreads();
    if (j < 4) {
        int r = j;
        float ts  = redS[r * 4 + 0]  + redS[r * 4 + 1]  + redS[r * 4 + 2]  + redS[r * 4 + 3];
        float ts2 = redS2[r * 4 + 0] + redS2[r * 4 + 1] + redS2[r * 4 + 2] + redS2[r * 4 + 3];
        float mean = ts * (1.f / DD);
        float var = ts2 * (1.f / DD) - mean * mean;
        mu[r] = mean;
        ri[r] = rsqrtf(var + 1e-5f);
    }
    __syncthreads();
    float g = gam[j], be = bet[j];
    #pragma unroll
    for (int r = 0; r < 4; ++r)
        x[(size_t)(r0 + r) * DD + j] = (val[r] - mu[r]) * ri[r] * g + be;
}

// standalone row-block GEMM + res + LN (proj) — measured-best E config (r3)
__global__ __launch_bounds__(256) void gemm4_res_ln(const float* __restrict__ A,
                                                    const float* __restrict__ Wt,
                                                    const float* __restrict__ bias,
                                                    const float* __restrict__ gam,
                                                    const float* __restrict__ bet,
                                                    float* __restrict__ x) {
    __shared__ float sm[1064];
    job_gemm_ln(sm, blockIdx.x * 4, A, Wt, bias, gam, bet, x);
}

// ================= job: sample one row — thread = (view, 8-channel group) =================
template <bool TRANSPOSED>
__device__ __forceinline__ void job_sample(float* sm, int row,
                                           const float* __restrict__ f0,
                                           const float* __restrict__ f1,
                                           const float* __restrict__ f2,
                                           const float* __restrict__ refb,
                                           const float* __restrict__ Rm,
                                           const float* __restrict__ Tm,
                                           const float* __restrict__ Km,
                                           float* __restrict__ fused) {
    float* sg    = sm;           // [8][3]
    float* sPart = sm + 32;      // [8][258]
    int t = threadIdx.x;
    int b = row / NQ;
    if (t < 8) {
        int bv = b * VV + t;
        const float* r = refb + (size_t)row * 3;
        const float* R = Rm + (size_t)bv * 9;
        const float* T = Tm + (size_t)bv * 3;
        const float* K = Km + (size_t)bv * 9;
        float p0 = R[0] * r[0] + R[1] * r[1] + R[2] * r[2] + T[0];
        float p1 = R[3] * r[0] + R[4] * r[1] + R[5] * r[2] + T[1];
        float p2 = R[6] * r[0] + R[7] * r[1] + R[8] * r[2] + T[2];
        float z = fmaxf(p2, 0.1f);
        float u  = p0 * K[0] / z + K[2];
        float vv = p1 * K[4] / z + K[5];
        float un = 2.f * u  / (float)(W_IMG - 1) - 1.f;
        float vn = 2.f * vv / (float)(H_IMG - 1) - 1.f;
        bool m = (un > -1.f) && (un < 1.f) && (vn > -1.f) && (vn < 1.f) && (p2 > 0.f);
        sg[t * 3 + 0] = un; sg[t * 3 + 1] = vn; sg[t * 3 + 2] = m ? 1.f : 0.f;
    }
    __syncthreads();
    int v = t >> 5, cg = t & 31;
    int ch0 = cg * 8;
    float acc[8] = {0, 0, 0, 0, 0, 0, 0, 0};
    float m = sg[v * 3 + 2];
    if (m != 0.f) {
        float un = sg[v * 3 + 0], vn = sg[v * 3 + 1];
        int bv = b * VV + v;
        const float* fl[3] = { f0, f1, f2 };
        const int Hs[3] = { 64, 32, 16 };
        #pragma unroll
        for (int lev = 0; lev < 3; ++lev) {
            int Hh = Hs[lev], Ww = Hs[lev];
            const float* f = fl[lev];
            float xx = (un + 1.f) * Ww * 0.5f - 0.5f;
            float yy = (vn + 1.f) * Hh * 0.5f - 0.5f;
            float x0f = floorf(xx), y0f = floorf(yy);
            int ix0 = (int)x0f, iy0 = (int)y0f;
            float wx1 = xx - x0f, wx0 = 1.f - wx1;
            float wy1 = yy - y0f, wy0 = 1.f - wy1;
            #pragma unroll
            for (int tap = 0; tap < 4; ++tap) {
                int ix = ix0 + (tap & 1);
                int iy = iy0 + (tap >> 1);
                float wgt = ((tap & 1) ? wx1 : wx0) * ((tap >> 1) ? wy1 : wy0);
                if (ix >= 0 && ix < Ww && iy >= 0 && iy < Hh) {
                    if (TRANSPOSED) {
                        const float* p = f + ((size_t)bv * Hh * Ww + (size_t)iy * Ww + ix) * DD + ch0;
                        float4 va = *(const float4*)p;
                        float4 vb = *(const float4*)(p + 4);
                        acc[0] = fmaf(wgt, va.x, acc[0]); acc[1] = fmaf(wgt, va.y, acc[1]);
                        acc[2] = fmaf(wgt, va.z, acc[2]); acc[3] = fmaf(wgt, va.w, acc[3]);
                        acc[4] = fmaf(wgt, vb.x, acc[4]); acc[5] = fmaf(wgt, vb.y, acc[5]);
                        acc[6] = fmaf(wgt, vb.z, acc[6]); acc[7] = fmaf(wgt, vb.w, acc[7]);
                    } else {
                        #pragma unroll
                        for (int c = 0; c < 8; ++c) {
                            float vv2 = f[(((size_t)bv * DD + ch0 + c) * Hh + iy) * Ww + ix];
                            acc[c] = fmaf(wgt, vv2, acc[c]);
                        }
                    }
                }
            }
        }
    }
    #pragma unroll
    for (int c = 0; c < 8; ++c) sPart[v * 258 + ch0 + c] = acc[c] * (1.f / 3.f);
    __syncthreads();
    float cnt = sg[2] + sg[5] + sg[8] + sg[11] + sg[14] + sg[17] + sg[20] + sg[23];
    float s = 0.f;
    #pragma unroll
    for (int v2 = 0; v2 < 8; ++v2) s += sPart[v2 * 258 + t];
    fused[(size_t)row * DD + t] = s / fmaxf(cnt, 1.f);
}

// ================= fused dispatch D: oproj+res+LN (168) + sample (672) =================
template <bool TRANSPOSED>
__global__ __launch_bounds__(256) void oproj_sample(const float* __restrict__ attn_o,
                                                    const float* __restrict__ Wo,
                                                    const float* __restrict__ bo,
                                                    const float* __restrict__ gam,
                                                    const float* __restrict__ bet,
                                                    float* __restrict__ x,
                                                    const float* __restrict__ f0,
                                                    const float* __restrict__ f1,
                                                    const float* __restrict__ f2,
                                                    const float* __restrict__ refb,
                                                    const float* __restrict__ Rm,
                                                    const float* __restrict__ Tm,
                                                    const float* __restrict__ Km,
                                                    float* __restrict__ fused) {
    __shared__ float sm[2112];
    if (blockIdx.x < 168)
        job_gemm_ln(sm, blockIdx.x * 4, attn_o, Wo, bo, gam, bet, x);
    else
        job_sample<TRANSPOSED>(sm, blockIdx.x - 168, f0, f1, f2, refb, Rm, Tm, Km, fused);
}

// ================= generic tiled GEMM. MODE 0 plain, 1 relu. grid (21, N/64, KS) =================
template <int MODE>
__global__ __launch_bounds__(256) void gemm_tile(const float* __restrict__ A,
                                                 const float* __restrict__ W,
                                                 const float* __restrict__ bias,
                                                 float* __restrict__ C,
                                                 int Ktot, int Kper, int Nout) {
    __shared__ float At[32][34];
    __shared__ float Wt[32][68];
    int t = threadIdx.x;
    int m0 = blockIdx.x * 32;
    int n0 = blockIdx.y * 64;
    int kz = blockIdx.z;
    int kofs = kz * Kper;
    int tx = t & 15, ty = t >> 4;
    int nc = n0 + tx * 4;
    float acc0[4], acc1[4];
    {
        float4 bv = make_float4(0.f, 0.f, 0.f, 0.f);
        if (bias && kz == 0) bv = *(const float4*)(bias + nc);
        acc0[0] = bv.x; acc0[1] = bv.y; acc0[2] = bv.z; acc0[3] = bv.w;
        acc1[0] = bv.x; acc1[1] = bv.y; acc1[2] = bv.z; acc1[3] = bv.w;
    }
    int am = t >> 3, ak4 = (t & 7) * 4;
    int ktiles = Kper >> 5;
    for (int kt = 0; kt < ktiles; ++kt) {
        int kk = kofs + kt * 32;
        __syncthreads();
        {
            float4 v = *(const float4*)(A + (size_t)(m0 + am) * Ktot + kk + ak4);
            At[ak4 + 0][am] = v.x; At[ak4 + 1][am] = v.y;
            At[ak4 + 2][am] = v.z; At[ak4 + 3][am] = v.w;
        }
        #pragma unroll
        for (int s = 0; s < 2; ++s) {
            int idx = t + s * 256;
            int wn = idx >> 3, wk4 = (idx & 7) * 4;
            float4 v = *(const float4*)(W + (size_t)(n0 + wn) * Ktot + kk + wk4);
            Wt[wk4 + 0][wn] = v.x; Wt[wk4 + 1][wn] = v.y;
            Wt[wk4 + 2][wn] = v.z; Wt[wk4 + 3][wn] = v.w;
        }
        __syncthreads();
        #pragma unroll
        for (int k = 0; k < 32; ++k) {
            float2 av = *(const float2*)&At[k][ty * 2];
            float4 wv = *(const float4*)&Wt[k][tx * 4];
            acc0[0] = fmaf(av.x, wv.x, acc0[0]); acc0[1] = fmaf(av.x, wv.y, acc0[1]);
            acc0[2] = fmaf(av.x, wv.z, acc0[2]); acc0[3] = fmaf(av.x, wv.w, acc0[3]);
            acc1[0] = fmaf(av.y, wv.x, acc1[0]); acc1[1] = fmaf(av.y, wv.y, acc1[1]);
            acc1[2] = fmaf(av.y, wv.z, acc1[2]); acc1[3] = fmaf(av.y, wv.w, acc1[3]);
        }
    }
    if (MODE == 1) {
        #pragma unroll
        for (int j = 0; j < 4; ++j) { acc0[j] = fmaxf(acc0[j], 0.f); acc1[j] = fmaxf(acc1[j], 0.f); }
    }
    int mr = m0 + ty * 2;
    float* Cb = C + (size_t)kz * MROWS * Nout;
    *(float4*)(Cb + (size_t)mr * Nout + nc)       = make_float4(acc0[0], acc0[1], acc0[2], acc0[3]);
    *(float4*)(Cb + (size_t)(mr + 1) * Nout + nc) = make_float4(acc1[0], acc1[1], acc1[2], acc1[3]);
}

// ================= residual + LN over NP k-split partials; xq = out + qp =================
template <int NP>
__global__ __launch_bounds__(256) void ln_res(float* __restrict__ x,
                                              const float* __restrict__ C,
                                              const float* __restrict__ gam,
                                              const float* __restrict__ bet,
                                              const float* __restrict__ qp,
                                              float* __restrict__ xq) {
    __shared__ float redS[4][4], redS2[4][4];
    __shared__ float mu[4], ri[4];
    int r0 = blockIdx.x * 4;
    int j = threadIdx.x;
    float val[4];
    #pragma unroll
    for (int r = 0; r < 4; ++r) {
        float a = x[(size_t)(r0 + r) * DD + j];
        #pragma unroll
        for (int p = 0; p < NP; ++p) a += C[(size_t)p * MROWS * DD + (size_t)(r0 + r) * DD + j];
        val[r] = a;
    }
    float s[4], s2[4];
    #pragma unroll
    for (int r = 0; r < 4; ++r) { s[r] = val[r]; s2[r] = val[r] * val[r]; }
    #pragma unroll
    for (int o = 32; o > 0; o >>= 1) {
        #pragma unroll
        for (int r = 0; r < 4; ++r) {
            s[r]  += __shfl_xor(s[r],  o);
            s2[r] += __shfl_xor(s2[r], o);
        }
    }
    int wid = j >> 6, lane = j & 63;
    if (lane == 0) {
        #pragma unroll
        for (int r = 0; r < 4; ++r) { redS[r][wid] = s[r]; redS2[r][wid] = s2[r]; }
    }
    __syncthreads();
    if (j < 4) {
        int r = j;
        float ts  = redS[r][0]  + redS[r][1]  + redS[r][2]  + redS[r][3];
        float ts2 = redS2[r][0] + redS2[r][1] + redS2[r][2] + redS2[r][3];
        float mean = ts * (1.f / DD);
        float var = ts2 * (1.f / DD) - mean * mean;
        mu[r] = mean;
        ri[r] = rsqrtf(var + 1e-5f);
    }
    __syncthreads();
    float g = gam[j], be = bet[j];
    #pragma unroll
    for (int r = 0; r < 4; ++r) {
        float o = (val[r] - mu[r]) * ri[r] * g + be;
        x[(size_t)(r0 + r) * DD + j] = o;
        if (qp) xq[(size_t)(r0 + r) * DD + j] = o + qp[(size_t)(r0 + r) * DD + j];
    }
}

extern "C" void kernel_launch(void* const* d_in, const int* in_sizes, int n_in,
                              void* d_out, int out_size, void* d_ws, size_t ws_size,
                              hipStream_t stream) {
    const float* tgt       = (const float*)d_in[0];
    const float* query_pos = (const float*)d_in[1];
    const float* refpts    = (const float*)d_in[2];
    const float* feat0     = (const float*)d_in[3];
    const float* feat1     = (const float*)d_in[4];
    const float* feat2     = (const float*)d_in[5];
    const float* camR      = (const float*)d_in[6];
    const float* camT      = (const float*)d_in[7];
    const float* camK      = (const float*)d_in[8];
    const float* Wqkv      = (const float*)d_in[9];
    const float* bqkv      = (const float*)d_in[10];
    const float* Wo        = (const float*)d_in[11];
    const float* bo        = (const float*)d_in[12];
    const float* ln1_g     = (const float*)d_in[13];
    const float* ln1_b     = (const float*)d_in[14];
    const float* Wproj     = (const float*)d_in[15];
    const float* bproj     = (const float*)d_in[16];
    const float* pn_g      = (const float*)d_in[17];
    const float* pn_b      = (const float*)d_in[18];
    const float* W1        = (const float*)d_in[19];
    const float* b1        = (const float*)d_in[20];
    const float* W2        = (const float*)d_in[21];
    const float* b2        = (const float*)d_in[22];
    const float* ln2_g     = (const float*)d_in[23];
    const float* ln2_b     = (const float*)d_in[24];
    const float* pose_W0   = (const float*)d_in[25];
    const float* pose_b0   = (const float*)d_in[26];
    const float* pose_W1   = (const float*)d_in[27];
    const float* pose_b1   = (const float*)d_in[28];
    const float* pose_W2   = (const float*)d_in[29];
    const float* pose_b2   = (const float*)d_in[30];
    const float* cls_W     = (const float*)d_in[31];
    const float* cls_b     = (const float*)d_in[32];
    float* out = (float*)d_out;

    float* w = (float*)d_ws;
    size_t off = 0;
    auto alloc = [&](size_t n) { float* p = w + off; off += n; return p; };
    float* x      = alloc((size_t)BQ * DD);
    float* xq     = alloc((size_t)BQ * DD);
    float* Qp     = alloc((size_t)BB * HEADS * NQ * HD);
    float* Kp     = alloc((size_t)BB * HEADS * NQ * HD);
    float* Vp     = alloc((size_t)BB * HEADS * NQ * HD);
    float* attn_o = alloc((size_t)BQ * DD);
    float* fused  = alloc((size_t)BQ * DD);
    float* ffh    = alloc((size_t)BQ * FF);
    float* ctmp   = alloc((size_t)4 * BQ * DD);
    float* refb   = alloc((size_t)BQ * 3 + 64);
    size_t base_floats = off;
    size_t featT_floats = (size_t)BB * VV * DD * (64 * 64 + 32 * 32 + 16 * 16);
    bool useT = ws_size >= (base_floats + featT_floats) * sizeof(float);
    float *fT0 = nullptr, *fT1 = nullptr, *fT2 = nullptr;
    if (useT) {
        fT0 = alloc((size_t)BB * VV * 64 * 64 * DD);
        fT1 = alloc((size_t)BB * VV * 32 * 32 * DD);
        fT2 = alloc((size_t)BB * VV * 16 * 16 * DD);
    }

    // init x, xq, refb (168 blocks). Separate dispatch: layer-0 qkv reads xq.
    init_k<<<168, 256, 0, stream>>>(tgt, query_pos, refpts, x, xq, refb);

    for (int l = 0; l < NL; ++l) {
        // A: qkv (252) + [l==0: full feature transpose (5376)] / [l>0: pose head (168)]
        if (l == 0 && useT) {
            qkv_tr<<<252 + 5376, 256, 0, stream>>>(
                xq, x, Wqkv, bqkv, Qp, Kp, Vp,
                feat0, feat1, feat2, fT0, fT1, fT2);
        } else {
            qkv_pose<<<252 + (l > 0 ? 168 : 0), 256, 0, stream>>>(
                xq, x, Wqkv + (size_t)l * 3 * DD * DD, bqkv + (size_t)l * 3 * DD, Qp, Kp, Vp,
                pose_W0, pose_b0, pose_W1, pose_b1, pose_W2, pose_b2, cls_W, cls_b,
                refb, out + (size_t)(l - 1) * BQ * 4);
        }
        // B: fused attention, 16-row tiles (352 blocks, 39 KB LDS — 2x parallelism of 176x61KB)
        attn16<<<352, 256, 0, stream>>>(Qp, Kp, Vp, attn_o);
        // D: oproj+res+LN1 (168) + sample (672)
        if (useT)
            oproj_sample<true><<<840, 256, 0, stream>>>(
                attn_o, Wo + (size_t)l * DD * DD, bo + (size_t)l * DD,
                ln1_g + (size_t)l * DD, ln1_b + (size_t)l * DD, x,
                fT0, fT1, fT2, refb, camR, camT, camK, fused);
        else
            oproj_sample<false><<<840, 256, 0, stream>>>(
                attn_o, Wo + (size_t)l * DD * DD, bo + (size_t)l * DD,
                ln1_g + (size_t)l * DD, ln1_b + (size_t)l * DD, x,
                feat0, feat1, feat2, refb, camR, camT, camK, fused);
        // E: proj-GEMM + res + LNpn (168 x 4-row — measured-best config, r3)
        gemm4_res_ln<<<BQ / 4, 256, 0, stream>>>(
            fused, Wproj + (size_t)l * DD * DD, bproj + (size_t)l * DD,
            pn_g + (size_t)l * DD, pn_b + (size_t)l * DD, x);
        // FFN1 (relu)
        gemm_tile<1><<<dim3(21, 16, 1), 256, 0, stream>>>(
            x, W1 + (size_t)l * FF * DD, b1 + (size_t)l * FF, ffh, DD, DD, FF);
        // FFN2 k-split (336 blocks) + ln_res (168): occupancy beats fusion here (r2).
        gemm_tile<0><<<dim3(21, 4, 4), 256, 0, stream>>>(
            ffh, W2 + (size_t)l * DD * FF, b2 + (size_t)l * DD, ctmp, FF, FF / 4, DD);
        ln_res<4><<<BQ / 4, 256, 0, stream>>>(
            x, ctmp, ln2_g + (size_t)l * DD, ln2_b + (size_t)l * DD, query_pos, xq);
    }
    // tail: pose head of layer NL-1
    pose_only<<<BQ / 4, 256, 0, stream>>>(
        x, pose_W0, pose_b0, pose_W1, pose_b1, pose_W2, pose_b2, cls_W, cls_b,
        refb, out + (size_t)(NL - 1) * BQ * 4);
}

// Round 8
// 804.166 us; speedup vs baseline: 1.1525x; 1.0474x over previous
//
#include <hip/hip_runtime.h>
#include <math.h>

#define BB 2
#define VV 8
#define NQ 336
#define DD 256
#define HEADS 8
#define HD 32
#define FF 1024
#define NL 6
#define BQ (BB*NQ)
#define W_IMG 512
#define H_IMG 512
#define MROWS BQ

// ================= job: 128ch x 32px transpose tile (5376 tiles) =================
// 16.9 KB LDS -> 8 blocks/CU (wave-capped). 512B-contiguous channel writes.
// At ~7.7 TB/s combined fabric throughput (r3 counters) — memory-system-limited.
__device__ __forceinline__ void job_transpose3(float* tile, int b,
                                               const float* __restrict__ f0,
                                               const float* __restrict__ f1,
                                               const float* __restrict__ f2,
                                               float* __restrict__ o0,
                                               float* __restrict__ o1,
                                               float* __restrict__ o2) {
    const float* src; float* dst; int HW, ptiles;
    if (b < 4096)      { src = f0; dst = o0; HW = 4096; ptiles = 128; }
    else if (b < 5120) { b -= 4096; src = f1; dst = o1; HW = 1024; ptiles = 32; }
    else               { b -= 5120; src = f2; dst = o2; HW = 256;  ptiles = 8;  }
    int cg = b & 1;
    int pt = (b >> 1) % ptiles;
    int bv = (b >> 1) / ptiles;
    int d0 = cg * 128, p0 = pt * 32;
    int t = threadIdx.x;
    int chb = t >> 3, px4 = (t & 7) * 4;
    #pragma unroll
    for (int pass = 0; pass < 4; ++pass) {
        int ch = pass * 32 + chb;
        float4 v = *(const float4*)(src + ((size_t)(bv * DD + d0 + ch)) * HW + p0 + px4);
        tile[ch * 33 + px4 + 0] = v.x; tile[ch * 33 + px4 + 1] = v.y;
        tile[ch * 33 + px4 + 2] = v.z; tile[ch * 33 + px4 + 3] = v.w;
    }
    __syncthreads();
    int c4 = (t & 31) * 4, pxb = t >> 5;
    #pragma unroll
    for (int pass = 0; pass < 4; ++pass) {
        int px = pass * 8 + pxb;
        float4 o;
        o.x = tile[(c4 + 0) * 33 + px];
        o.y = tile[(c4 + 1) * 33 + px];
        o.z = tile[(c4 + 2) * 33 + px];
        o.w = tile[(c4 + 3) * 33 + px];
        *(float4*)(dst + ((size_t)bv * HW + p0 + px) * DD + d0 + c4) = o;
    }
}

// ================= init (168 blocks) =================
__global__ __launch_bounds__(256) void init_k(const float* __restrict__ tgt,
                                              const float* __restrict__ qp,
                                              const float* __restrict__ refpts,
                                              float* __restrict__ x,
                                              float* __restrict__ xq,
                                              float* __restrict__ refb) {
    int i = blockIdx.x * 256 + threadIdx.x;
    float4 tv = ((const float4*)tgt)[i];
    float4 qv = ((const float4*)qp)[i];
    ((float4*)x)[i] = tv;
    ((float4*)xq)[i] = make_float4(tv.x + qv.x, tv.y + qv.y, tv.z + qv.z, tv.w + qv.w);
    if (i < BQ * 3) refb[i] = refpts[i];
}

// ================= job: 32x64 qkv tile, head-packed output =================
__device__ __forceinline__ void job_qkv(float* sm, int bid,
                                        const float* __restrict__ Aq,
                                        const float* __restrict__ Ax,
                                        const float* __restrict__ W,
                                        const float* __restrict__ bias,
                                        float* __restrict__ Qp,
                                        float* __restrict__ Kp,
                                        float* __restrict__ Vp) {
    float* At = sm;            // [32][34]
    float* Wt = sm + 1088;     // [32][68]
    int t = threadIdx.x;
    int m0 = (bid % 21) * 32;
    int ncol = bid / 21;
    int n0 = ncol * 64;
    const float* A = (ncol < 8) ? Aq : Ax;
    int tx = t & 15, ty = t >> 4;
    int nc = n0 + tx * 4;
    float acc0[4], acc1[4];
    {
        float4 bv = *(const float4*)(bias + nc);
        acc0[0] = bv.x; acc0[1] = bv.y; acc0[2] = bv.z; acc0[3] = bv.w;
        acc1[0] = bv.x; acc1[1] = bv.y; acc1[2] = bv.z; acc1[3] = bv.w;
    }
    int am = t >> 3, ak4 = (t & 7) * 4;
    for (int kt = 0; kt < 8; ++kt) {
        int kk = kt * 32;
        __syncthreads();
        {
            float4 v = *(const float4*)(A + (size_t)(m0 + am) * DD + kk + ak4);
            At[(ak4 + 0) * 34 + am] = v.x; At[(ak4 + 1) * 34 + am] = v.y;
            At[(ak4 + 2) * 34 + am] = v.z; At[(ak4 + 3) * 34 + am] = v.w;
        }
        #pragma unroll
        for (int s = 0; s < 2; ++s) {
            int idx = t + s * 256;
            int wn = idx >> 3, wk4 = (idx & 7) * 4;
            float4 v = *(const float4*)(W + (size_t)(n0 + wn) * DD + kk + wk4);
            Wt[(wk4 + 0) * 68 + wn] = v.x; Wt[(wk4 + 1) * 68 + wn] = v.y;
            Wt[(wk4 + 2) * 68 + wn] = v.z; Wt[(wk4 + 3) * 68 + wn] = v.w;
        }
        __syncthreads();
        #pragma unroll
        for (int k = 0; k < 32; ++k) {
            float2 av = *(const float2*)&At[k * 34 + ty * 2];
            float4 wv = *(const float4*)&Wt[k * 68 + tx * 4];
            acc0[0] = fmaf(av.x, wv.x, acc0[0]); acc0[1] = fmaf(av.x, wv.y, acc0[1]);
            acc0[2] = fmaf(av.x, wv.z, acc0[2]); acc0[3] = fmaf(av.x, wv.w, acc0[3]);
            acc1[0] = fmaf(av.y, wv.x, acc1[0]); acc1[1] = fmaf(av.y, wv.y, acc1[1]);
            acc1[2] = fmaf(av.y, wv.z, acc1[2]); acc1[3] = fmaf(av.y, wv.w, acc1[3]);
        }
    }
    int mr = m0 + ty * 2;
    int kind = nc >> 8;
    float* base = kind == 0 ? Qp : (kind == 1 ? Kp : Vp);
    int h = (nc >> 5) & 7, d4 = nc & 31;
    #pragma unroll
    for (int i = 0; i < 2; ++i) {
        int m = mr + i;
        int b = m / NQ, q = m - b * NQ;
        float* p = base + ((size_t)((b << 3) + h) * NQ + q) * HD + d4;
        float* src = i == 0 ? acc0 : acc1;
        *(float4*)p = make_float4(src[0], src[1], src[2], src[3]);
    }
}

// ================= job: pose MLP + heads for 4 rows =================
__device__ __forceinline__ void job_pose(float* sm, int job,
                                         const float* __restrict__ x,
                                         const float* __restrict__ W0, const float* __restrict__ b0,
                                         const float* __restrict__ W1p, const float* __restrict__ b1p,
                                         const float* __restrict__ W2p, const float* __restrict__ b2p,
                                         const float* __restrict__ cW, const float* __restrict__ cb,
                                         float* __restrict__ refb, float* __restrict__ outp) {
    float* sX  = sm;          // 1024
    float* sH  = sm + 1024;   // 1024
    float* red = sm + 2048;   // 64
    int r0 = job * 4;
    int tid = threadIdx.x;
    ((float4*)sX)[tid] = ((const float4*)(x + (size_t)r0 * DD))[tid];
    __syncthreads();
    {
        float a0 = b0[tid], a1 = a0, a2 = a0, a3 = a0;
        const float* wp = W0 + (size_t)tid * DD;
        for (int k = 0; k < DD; k += 4) {
            float4 w  = *(const float4*)(wp + k);
            float4 x0 = *(const float4*)(sX + 0 * DD + k);
            float4 x1 = *(const float4*)(sX + 1 * DD + k);
            float4 x2 = *(const float4*)(sX + 2 * DD + k);
            float4 x3 = *(const float4*)(sX + 3 * DD + k);
            a0 = fmaf(x0.x, w.x, a0); a0 = fmaf(x0.y, w.y, a0); a0 = fmaf(x0.z, w.z, a0); a0 = fmaf(x0.w, w.w, a0);
            a1 = fmaf(x1.x, w.x, a1); a1 = fmaf(x1.y, w.y, a1); a1 = fmaf(x1.z, w.z, a1); a1 = fmaf(x1.w, w.w, a1);
            a2 = fmaf(x2.x, w.x, a2); a2 = fmaf(x2.y, w.y, a2); a2 = fmaf(x2.z, w.z, a2); a2 = fmaf(x2.w, w.w, a2);
            a3 = fmaf(x3.x, w.x, a3); a3 = fmaf(x3.y, w.y, a3); a3 = fmaf(x3.z, w.z, a3); a3 = fmaf(x3.w, w.w, a3);
        }
        sH[0 * DD + tid] = fmaxf(a0, 0.f);
        sH[1 * DD + tid] = fmaxf(a1, 0.f);
        sH[2 * DD + tid] = fmaxf(a2, 0.f);
        sH[3 * DD + tid] = fmaxf(a3, 0.f);
    }
    __syncthreads();
    float h[4];
    {
        float a0 = b1p[tid], a1 = a0, a2 = a0, a3 = a0;
        const float* wp = W1p + (size_t)tid * DD;
        for (int k = 0; k < DD; k += 4) {
            float4 w  = *(const float4*)(wp + k);
            float4 x0 = *(const float4*)(sH + 0 * DD + k);
            float4 x1 = *(const float4*)(sH + 1 * DD + k);
            float4 x2 = *(const float4*)(sH + 2 * DD + k);
            float4 x3 = *(const float4*)(sH + 3 * DD + k);
            a0 = fmaf(x0.x, w.x, a0); a0 = fmaf(x0.y, w.y, a0); a0 = fmaf(x0.z, w.z, a0); a0 = fmaf(x0.w, w.w, a0);
            a1 = fmaf(x1.x, w.x, a1); a1 = fmaf(x1.y, w.y, a1); a1 = fmaf(x1.z, w.z, a1); a1 = fmaf(x1.w, w.w, a1);
            a2 = fmaf(x2.x, w.x, a2); a2 = fmaf(x2.y, w.y, a2); a2 = fmaf(x2.z, w.z, a2); a2 = fmaf(x2.w, w.w, a2);
            a3 = fmaf(x3.x, w.x, a3); a3 = fmaf(x3.y, w.y, a3); a3 = fmaf(x3.z, w.z, a3); a3 = fmaf(x3.w, w.w, a3);
        }
        h[0] = fmaxf(a0, 0.f); h[1] = fmaxf(a1, 0.f); h[2] = fmaxf(a2, 0.f); h[3] = fmaxf(a3, 0.f);
    }
    float w2a = W2p[tid], w2b = W2p[DD + tid], w2c = W2p[2 * DD + tid], cw = cW[tid];
    float v[4][4];
    #pragma unroll
    for (int r = 0; r < 4; ++r) {
        v[r][0] = h[r] * w2a;
        v[r][1] = h[r] * w2b;
        v[r][2] = h[r] * w2c;
        v[r][3] = sX[r * DD + tid] * cw;
    }
    #pragma unroll
    for (int o2 = 32; o2 > 0; o2 >>= 1) {
        #pragma unroll
        for (int r = 0; r < 4; ++r) {
            #pragma unroll
            for (int c = 0; c < 4; ++c) v[r][c] += __shfl_xor(v[r][c], o2);
        }
    }
    int wid = tid >> 6, lane = tid & 63;
    if (lane == 0) {
        #pragma unroll
        for (int r = 0; r < 4; ++r) {
            #pragma unroll
            for (int c = 0; c < 4; ++c) red[(r * 4 + c) * 4 + wid] = v[r][c];
        }
    }
    __syncthreads();
    if (tid < 4) {
        int r = tid;
        float d0 = red[(r * 4 + 0) * 4 + 0] + red[(r * 4 + 0) * 4 + 1] + red[(r * 4 + 0) * 4 + 2] + red[(r * 4 + 0) * 4 + 3] + b2p[0];
        float d1 = red[(r * 4 + 1) * 4 + 0] + red[(r * 4 + 1) * 4 + 1] + red[(r * 4 + 1) * 4 + 2] + red[(r * 4 + 1) * 4 + 3] + b2p[1];
        float d2 = red[(r * 4 + 2) * 4 + 0] + red[(r * 4 + 2) * 4 + 1] + red[(r * 4 + 2) * 4 + 2] + red[(r * 4 + 2) * 4 + 3] + b2p[2];
        float cl = red[(r * 4 + 3) * 4 + 0] + red[(r * 4 + 3) * 4 + 1] + red[(r * 4 + 3) * 4 + 2] + red[(r * 4 + 3) * 4 + 3] + cb[0];
        int row = r0 + r;
        float rx = refb[(size_t)row * 3 + 0] + d0;
        float ry = refb[(size_t)row * 3 + 1] + d1;
        float rz = refb[(size_t)row * 3 + 2] + d2;
        refb[(size_t)row * 3 + 0] = rx;
        refb[(size_t)row * 3 + 1] = ry;
        refb[(size_t)row * 3 + 2] = rz;
        outp[(size_t)row * 4 + 0] = cl;
        outp[(size_t)row * 4 + 1] = rx;
        outp[(size_t)row * 4 + 2] = ry;
        outp[(size_t)row * 4 + 3] = rz;
    }
}

// ================= fused dispatch A: qkv (252) + pose of prev layer (168) =================
__global__ __launch_bounds__(256) void qkv_pose(const float* __restrict__ xq,
                                                const float* __restrict__ x,
                                                const float* __restrict__ Wqkv,
                                                const float* __restrict__ bqkv,
                                                float* __restrict__ Qp,
                                                float* __restrict__ Kp,
                                                float* __restrict__ Vp,
                                                const float* __restrict__ pW0, const float* __restrict__ pb0,
                                                const float* __restrict__ pW1, const float* __restrict__ pb1,
                                                const float* __restrict__ pW2, const float* __restrict__ pb2,
                                                const float* __restrict__ cW, const float* __restrict__ cb,
                                                float* __restrict__ refb, float* __restrict__ outp) {
    __shared__ float sm[3264];
    if (blockIdx.x < 252)
        job_qkv(sm, blockIdx.x, xq, x, Wqkv, bqkv, Qp, Kp, Vp);
    else
        job_pose(sm, blockIdx.x - 252, x, pW0, pb0, pW1, pb1, pW2, pb2, cW, cb, refb, outp);
}

// ================= layer-0 variant: qkv (252) + full transpose (5376) =================
__global__ __launch_bounds__(256) void qkv_tr(const float* __restrict__ xq,
                                              const float* __restrict__ x,
                                              const float* __restrict__ Wqkv,
                                              const float* __restrict__ bqkv,
                                              float* __restrict__ Qp,
                                              float* __restrict__ Kp,
                                              float* __restrict__ Vp,
                                              const float* __restrict__ f0,
                                              const float* __restrict__ f1,
                                              const float* __restrict__ f2,
                                              float* __restrict__ o0,
                                              float* __restrict__ o1,
                                              float* __restrict__ o2) {
    __shared__ float sm[4224];
    if (blockIdx.x < 252)
        job_qkv(sm, blockIdx.x, xq, x, Wqkv, bqkv, Qp, Kp, Vp);
    else
        job_transpose3(sm, blockIdx.x - 252, f0, f1, f2, o0, o1, o2);
}

// standalone pose (tail)
__global__ __launch_bounds__(256) void pose_only(const float* __restrict__ x,
                                                 const float* __restrict__ pW0, const float* __restrict__ pb0,
                                                 const float* __restrict__ pW1, const float* __restrict__ pb1,
                                                 const float* __restrict__ pW2, const float* __restrict__ pb2,
                                                 const float* __restrict__ cW, const float* __restrict__ cb,
                                                 float* __restrict__ refb, float* __restrict__ outp) {
    __shared__ float sm[2112];
    job_pose(sm, blockIdx.x, x, pW0, pb0, pW1, pb1, pW2, pb2, cW, cb, refb, outp);
}

// ================= 16-row fused attention (scores + exact softmax + PV in LDS) =================
// 352 blocks (16 bh x 22 q-tiles), 39 KB LDS. Measured neutral vs 32-row (r7), keeps LDS free.
__global__ __launch_bounds__(256) void attn16(const float* __restrict__ Qp,
                                              const float* __restrict__ Kp,
                                              const float* __restrict__ Vp,
                                              float* __restrict__ O) {
    __shared__ float sm[9744];
    float* S   = sm;            // [16][344]  5504
    float* KT  = sm + 5504;     // [32][68]   2176
    float* U   = sm + 7680;     // union: QT [32][20]=640 / Vt [64][32]=2048
    float* inv = sm + 9728;     // [16]
    int blk = blockIdx.x;
    int bh = blk & 15, qt = blk >> 4;   // qt 0..21
    int t = threadIdx.x;
    const float scale = 0.17677669529663687f;
    const float* Qb = Qp + (size_t)bh * NQ * HD;
    const float* Kb = Kp + (size_t)bh * NQ * HD;
    const float* Vb = Vp + (size_t)bh * NQ * HD;
    if (t < 128) {
        int ql = t >> 3, d4 = (t & 7) * 4;
        int qg = qt * 16 + ql;
        float4 v = (qg < NQ) ? *(const float4*)(Qb + (size_t)qg * HD + d4)
                             : make_float4(0.f, 0.f, 0.f, 0.f);
        U[(d4 + 0) * 20 + ql] = v.x * scale;
        U[(d4 + 1) * 20 + ql] = v.y * scale;
        U[(d4 + 2) * 20 + ql] = v.z * scale;
        U[(d4 + 3) * 20 + ql] = v.w * scale;
    }
    int r = t >> 4, tx = t & 15;
    for (int kt = 0; kt < 6; ++kt) {
        __syncthreads();
        #pragma unroll
        for (int s = 0; s < 2; ++s) {
            int idx = t + s * 256;
            int kl = idx >> 3, d4 = (idx & 7) * 4;
            int kg = kt * 64 + kl;
            float4 v = (kg < NQ) ? *(const float4*)(Kb + (size_t)kg * HD + d4)
                                 : make_float4(0.f, 0.f, 0.f, 0.f);
            KT[(d4 + 0) * 68 + kl] = v.x; KT[(d4 + 1) * 68 + kl] = v.y;
            KT[(d4 + 2) * 68 + kl] = v.z; KT[(d4 + 3) * 68 + kl] = v.w;
        }
        __syncthreads();
        float a0 = 0.f, a1 = 0.f, a2 = 0.f, a3 = 0.f;
        #pragma unroll
        for (int k = 0; k < 32; ++k) {
            float qv = U[k * 20 + r];
            float4 kv = *(const float4*)&KT[k * 68 + tx * 4];
            a0 = fmaf(qv, kv.x, a0); a1 = fmaf(qv, kv.y, a1);
            a2 = fmaf(qv, kv.z, a2); a3 = fmaf(qv, kv.w, a3);
        }
        int col = kt * 64 + tx * 4;
        if (col < NQ)
            *(float4*)&S[r * 344 + col] = make_float4(a0, a1, a2, a3);
    }
    __syncthreads();
    {
        float* row = S + (size_t)r * 344;
        float m = -1e30f;
        for (int i = 0; i < 21; ++i) m = fmaxf(m, row[tx + 16 * i]);
        m = fmaxf(m, __shfl_xor(m, 1));
        m = fmaxf(m, __shfl_xor(m, 2));
        m = fmaxf(m, __shfl_xor(m, 4));
        m = fmaxf(m, __shfl_xor(m, 8));
        float ssum = 0.f;
        for (int i = 0; i < 21; ++i) {
            float e = expf(row[tx + 16 * i] - m);
            row[tx + 16 * i] = e;
            ssum += e;
        }
        ssum += __shfl_xor(ssum, 1);
        ssum += __shfl_xor(ssum, 2);
        ssum += __shfl_xor(ssum, 4);
        ssum += __shfl_xor(ssum, 8);
        if (tx == 0) inv[r] = 1.f / ssum;
    }
    int d0 = tx * 2;
    float acc0 = 0.f, acc1 = 0.f;
    for (int kt = 0; kt < 6; ++kt) {
        __syncthreads();
        #pragma unroll
        for (int s = 0; s < 2; ++s) {
            int idx = t + s * 256;
            int kl = idx >> 3, d4 = (idx & 7) * 4;
            int kg = kt * 64 + kl;
            float4 v = (kg < NQ) ? *(const float4*)(Vb + (size_t)kg * HD + d4)
                                 : make_float4(0.f, 0.f, 0.f, 0.f);
            *(float4*)&U[kl * 32 + d4] = v;   // Vt
        }
        __syncthreads();
        int kmax = (kt == 5) ? 16 : 64;       // keys 320..335 only (NQ=336)
        const float* Srow = S + (size_t)r * 344 + kt * 64;
        #pragma unroll 8
        for (int kk = 0; kk < kmax; ++kk) {
            float p = Srow[kk];
            float2 vv = *(const float2*)&U[kk * 32 + d0];
            acc0 = fmaf(p, vv.x, acc0); acc1 = fmaf(p, vv.y, acc1);
        }
    }
    float iv = inv[r];
    int qg = qt * 16 + r;
    int b = bh >> 3, h = bh & 7;
    if (qg < NQ)
        *(float2*)(O + ((size_t)(b * NQ + qg)) * DD + h * HD + d0) =
            make_float2(acc0 * iv, acc1 * iv);
}

// ================= job: row-block GEMM(K=256,N=256) + residual + LN (4 rows) =================
// (used by oproj inside oproj_sample, where it hides under the sample blocks)
__device__ __forceinline__ void job_gemm_ln(float* sm, int r0,
                                            const float* __restrict__ A,
                                            const float* __restrict__ Wt,
                                            const float* __restrict__ bias,
                                            const float* __restrict__ gam,
                                            const float* __restrict__ bet,
                                            float* __restrict__ x) {
    float* sA    = sm;          // 1024
    float* redS  = sm + 1024;   // 16
    float* redS2 = sm + 1040;   // 16
    float* mu    = sm + 1056;   // 4
    float* ri    = sm + 1060;   // 4
    int j = threadIdx.x;
    ((float4*)sA)[j] = ((const float4*)(A + (size_t)r0 * DD))[j];
    __syncthreads();
    float acc0 = bias[j], acc1 = acc0, acc2 = acc0, acc3 = acc0;
    const float* wp = Wt + (size_t)j * DD;
    for (int k = 0; k < DD; k += 4) {
        float4 w  = *(const float4*)(wp + k);
        float4 a0 = *(const float4*)(sA + 0 * DD + k);
        float4 a1 = *(const float4*)(sA + 1 * DD + k);
        float4 a2 = *(const float4*)(sA + 2 * DD + k);
        float4 a3 = *(const float4*)(sA + 3 * DD + k);
        acc0 = fmaf(a0.x, w.x, acc0); acc0 = fmaf(a0.y, w.y, acc0); acc0 = fmaf(a0.z, w.z, acc0); acc0 = fmaf(a0.w, w.w, acc0);
        acc1 = fmaf(a1.x, w.x, acc1); acc1 = fmaf(a1.y, w.y, acc1); acc1 = fmaf(a1.z, w.z, acc1); acc1 = fmaf(a1.w, w.w, acc1);
        acc2 = fmaf(a2.x, w.x, acc2); acc2 = fmaf(a2.y, w.y, acc2); acc2 = fmaf(a2.z, w.z, acc2); acc2 = fmaf(a2.w, w.w, acc2);
        acc3 = fmaf(a3.x, w.x, acc3); acc3 = fmaf(a3.y, w.y, acc3); acc3 = fmaf(a3.z, w.z, acc3); acc3 = fmaf(a3.w, w.w, acc3);
    }
    float val[4];
    val[0] = x[(size_t)(r0 + 0) * DD + j] + acc0;
    val[1] = x[(size_t)(r0 + 1) * DD + j] + acc1;
    val[2] = x[(size_t)(r0 + 2) * DD + j] + acc2;
    val[3] = x[(size_t)(r0 + 3) * DD + j] + acc3;
    float s[4], s2[4];
    #pragma unroll
    for (int r = 0; r < 4; ++r) { s[r] = val[r]; s2[r] = val[r] * val[r]; }
    #pragma unroll
    for (int o2 = 32; o2 > 0; o2 >>= 1) {
        #pragma unroll
        for (int r = 0; r < 4; ++r) {
            s[r]  += __shfl_xor(s[r],  o2);
            s2[r] += __shfl_xor(s2[r], o2);
        }
    }
    int wid = j >> 6, lane = j & 63;
    if (lane == 0) {
        #pragma unroll
        for (int r = 0; r < 4; ++r) { redS[r * 4 + wid] = s[r]; redS2[r * 4 + wid] = s2[r]; }
    }
    __syncthreads();
    if (j < 4) {
        int r = j;
        float ts  = redS[r * 4 + 0]  + redS[r * 4 + 1]  + redS[r * 4 + 2]  + redS[r * 4 + 3];
        float ts2 = redS2[r * 4 + 0] + redS2[r * 4 + 1] + redS2[r * 4 + 2] + redS2[r * 4 + 3];
        float mean = ts * (1.f / DD);
        float var = ts2 * (1.f / DD) - mean * mean;
        mu[r] = mean;
        ri[r] = rsqrtf(var + 1e-5f);
    }
    __syncthreads();
    float g = gam[j], be = bet[j];
    #pragma unroll
    for (int r = 0; r < 4; ++r)
        x[(size_t)(r0 + r) * DD + j] = (val[r] - mu[r]) * ri[r] * g + be;
}

// ================= job: sample one row — thread = (view, 8-channel group) =================
template <bool TRANSPOSED>
__device__ __forceinline__ void job_sample(float* sm, int row,
                                           const float* __restrict__ f0,
                                           const float* __restrict__ f1,
                                           const float* __restrict__ f2,
                                           const float* __restrict__ refb,
                                           const float* __restrict__ Rm,
                                           const float* __restrict__ Tm,
                                           const float* __restrict__ Km,
                                           float* __restrict__ fused) {
    float* sg    = sm;           // [8][3]
    float* sPart = sm + 32;      // [8][258]
    int t = threadIdx.x;
    int b = row / NQ;
    if (t < 8) {
        int bv = b * VV + t;
        const float* r = refb + (size_t)row * 3;
        const float* R = Rm + (size_t)bv * 9;
        const float* T = Tm + (size_t)bv * 3;
        const float* K = Km + (size_t)bv * 9;
        float p0 = R[0] * r[0] + R[1] * r[1] + R[2] * r[2] + T[0];
        float p1 = R[3] * r[0] + R[4] * r[1] + R[5] * r[2] + T[1];
        float p2 = R[6] * r[0] + R[7] * r[1] + R[8] * r[2] + T[2];
        float z = fmaxf(p2, 0.1f);
        float u  = p0 * K[0] / z + K[2];
        float vv = p1 * K[4] / z + K[5];
        float un = 2.f * u  / (float)(W_IMG - 1) - 1.f;
        float vn = 2.f * vv / (float)(H_IMG - 1) - 1.f;
        bool m = (un > -1.f) && (un < 1.f) && (vn > -1.f) && (vn < 1.f) && (p2 > 0.f);
        sg[t * 3 + 0] = un; sg[t * 3 + 1] = vn; sg[t * 3 + 2] = m ? 1.f : 0.f;
    }
    __syncthreads();
    int v = t >> 5, cg = t & 31;
    int ch0 = cg * 8;
    float acc[8] = {0, 0, 0, 0, 0, 0, 0, 0};
    float m = sg[v * 3 + 2];
    if (m != 0.f) {
        float un = sg[v * 3 + 0], vn = sg[v * 3 + 1];
        int bv = b * VV + v;
        const float* fl[3] = { f0, f1, f2 };
        const int Hs[3] = { 64, 32, 16 };
        #pragma unroll
        for (int lev = 0; lev < 3; ++lev) {
            int Hh = Hs[lev], Ww = Hs[lev];
            const float* f = fl[lev];
            float xx = (un + 1.f) * Ww * 0.5f - 0.5f;
            float yy = (vn + 1.f) * Hh * 0.5f - 0.5f;
            float x0f = floorf(xx), y0f = floorf(yy);
            int ix0 = (int)x0f, iy0 = (int)y0f;
            float wx1 = xx - x0f, wx0 = 1.f - wx1;
            float wy1 = yy - y0f, wy0 = 1.f - wy1;
            #pragma unroll
            for (int tap = 0; tap < 4; ++tap) {
                int ix = ix0 + (tap & 1);
                int iy = iy0 + (tap >> 1);
                float wgt = ((tap & 1) ? wx1 : wx0) * ((tap >> 1) ? wy1 : wy0);
                if (ix >= 0 && ix < Ww && iy >= 0 && iy < Hh) {
                    if (TRANSPOSED) {
                        const float* p = f + ((size_t)bv * Hh * Ww + (size_t)iy * Ww + ix) * DD + ch0;
                        float4 va = *(const float4*)p;
                        float4 vb = *(const float4*)(p + 4);
                        acc[0] = fmaf(wgt, va.x, acc[0]); acc[1] = fmaf(wgt, va.y, acc[1]);
                        acc[2] = fmaf(wgt, va.z, acc[2]); acc[3] = fmaf(wgt, va.w, acc[3]);
                        acc[4] = fmaf(wgt, vb.x, acc[4]); acc[5] = fmaf(wgt, vb.y, acc[5]);
                        acc[6] = fmaf(wgt, vb.z, acc[6]); acc[7] = fmaf(wgt, vb.w, acc[7]);
                    } else {
                        #pragma unroll
                        for (int c = 0; c < 8; ++c) {
                            float vv2 = f[(((size_t)bv * DD + ch0 + c) * Hh + iy) * Ww + ix];
                            acc[c] = fmaf(wgt, vv2, acc[c]);
                        }
                    }
                }
            }
        }
    }
    #pragma unroll
    for (int c = 0; c < 8; ++c) sPart[v * 258 + ch0 + c] = acc[c] * (1.f / 3.f);
    __syncthreads();
    float cnt = sg[2] + sg[5] + sg[8] + sg[11] + sg[14] + sg[17] + sg[20] + sg[23];
    float s = 0.f;
    #pragma unroll
    for (int v2 = 0; v2 < 8; ++v2) s += sPart[v2 * 258 + t];
    fused[(size_t)row * DD + t] = s / fmaxf(cnt, 1.f);
}

// ================= fused dispatch D: oproj+res+LN (168) + sample (672) =================
template <bool TRANSPOSED>
__global__ __launch_bounds__(256) void oproj_sample(const float* __restrict__ attn_o,
                                                    const float* __restrict__ Wo,
                                                    const float* __restrict__ bo,
                                                    const float* __restrict__ gam,
                                                    const float* __restrict__ bet,
                                                    float* __restrict__ x,
                                                    const float* __restrict__ f0,
                                                    const float* __restrict__ f1,
                                                    const float* __restrict__ f2,
                                                    const float* __restrict__ refb,
                                                    const float* __restrict__ Rm,
                                                    const float* __restrict__ Tm,
                                                    const float* __restrict__ Km,
                                                    float* __restrict__ fused) {
    __shared__ float sm[2112];
    if (blockIdx.x < 168)
        job_gemm_ln(sm, blockIdx.x * 4, attn_o, Wo, bo, gam, bet, x);
    else
        job_sample<TRANSPOSED>(sm, blockIdx.x - 168, f0, f1, f2, refb, Rm, Tm, Km, fused);
}

// ================= generic tiled GEMM. MODE 0 plain, 1 relu. grid (21, N/64, KS) =================
template <int MODE>
__global__ __launch_bounds__(256) void gemm_tile(const float* __restrict__ A,
                                                 const float* __restrict__ W,
                                                 const float* __restrict__ bias,
                                                 float* __restrict__ C,
                                                 int Ktot, int Kper, int Nout) {
    __shared__ float At[32][34];
    __shared__ float Wt[32][68];
    int t = threadIdx.x;
    int m0 = blockIdx.x * 32;
    int n0 = blockIdx.y * 64;
    int kz = blockIdx.z;
    int kofs = kz * Kper;
    int tx = t & 15, ty = t >> 4;
    int nc = n0 + tx * 4;
    float acc0[4], acc1[4];
    {
        float4 bv = make_float4(0.f, 0.f, 0.f, 0.f);
        if (bias && kz == 0) bv = *(const float4*)(bias + nc);
        acc0[0] = bv.x; acc0[1] = bv.y; acc0[2] = bv.z; acc0[3] = bv.w;
        acc1[0] = bv.x; acc1[1] = bv.y; acc1[2] = bv.z; acc1[3] = bv.w;
    }
    int am = t >> 3, ak4 = (t & 7) * 4;
    int ktiles = Kper >> 5;
    for (int kt = 0; kt < ktiles; ++kt) {
        int kk = kofs + kt * 32;
        __syncthreads();
        {
            float4 v = *(const float4*)(A + (size_t)(m0 + am) * Ktot + kk + ak4);
            At[ak4 + 0][am] = v.x; At[ak4 + 1][am] = v.y;
            At[ak4 + 2][am] = v.z; At[ak4 + 3][am] = v.w;
        }
        #pragma unroll
        for (int s = 0; s < 2; ++s) {
            int idx = t + s * 256;
            int wn = idx >> 3, wk4 = (idx & 7) * 4;
            float4 v = *(const float4*)(W + (size_t)(n0 + wn) * Ktot + kk + wk4);
            Wt[wk4 + 0][wn] = v.x; Wt[wk4 + 1][wn] = v.y;
            Wt[wk4 + 2][wn] = v.z; Wt[wk4 + 3][wn] = v.w;
        }
        __syncthreads();
        #pragma unroll
        for (int k = 0; k < 32; ++k) {
            float2 av = *(const float2*)&At[k][ty * 2];
            float4 wv = *(const float4*)&Wt[k][tx * 4];
            acc0[0] = fmaf(av.x, wv.x, acc0[0]); acc0[1] = fmaf(av.x, wv.y, acc0[1]);
            acc0[2] = fmaf(av.x, wv.z, acc0[2]); acc0[3] = fmaf(av.x, wv.w, acc0[3]);
            acc1[0] = fmaf(av.y, wv.x, acc1[0]); acc1[1] = fmaf(av.y, wv.y, acc1[1]);
            acc1[2] = fmaf(av.y, wv.z, acc1[2]); acc1[3] = fmaf(av.y, wv.w, acc1[3]);
        }
    }
    if (MODE == 1) {
        #pragma unroll
        for (int j = 0; j < 4; ++j) { acc0[j] = fmaxf(acc0[j], 0.f); acc1[j] = fmaxf(acc1[j], 0.f); }
    }
    int mr = m0 + ty * 2;
    float* Cb = C + (size_t)kz * MROWS * Nout;
    *(float4*)(Cb + (size_t)mr * Nout + nc)       = make_float4(acc0[0], acc0[1], acc0[2], acc0[3]);
    *(float4*)(Cb + (size_t)(mr + 1) * Nout + nc) = make_float4(acc1[0], acc1[1], acc1[2], acc1[3]);
}

// ================= residual + LN over NP k-split partials; optional xq = out + qp =================
template <int NP>
__global__ __launch_bounds__(256) void ln_res(float* __restrict__ x,
                                              const float* __restrict__ C,
                                              const float* __restrict__ gam,
                                              const float* __restrict__ bet,
                                              const float* __restrict__ qp,
                                              float* __restrict__ xq) {
    __shared__ float redS[4][4], redS2[4][4];
    __shared__ float mu[4], ri[4];
    int r0 = blockIdx.x * 4;
    int j = threadIdx.x;
    float val[4];
    #pragma unroll
    for (int r = 0; r < 4; ++r) {
        float a = x[(size_t)(r0 + r) * DD + j];
        #pragma unroll
        for (int p = 0; p < NP; ++p) a += C[(size_t)p * MROWS * DD + (size_t)(r0 + r) * DD + j];
        val[r] = a;
    }
    float s[4], s2[4];
    #pragma unroll
    for (int r = 0; r < 4; ++r) { s[r] = val[r]; s2[r] = val[r] * val[r]; }
    #pragma unroll
    for (int o = 32; o > 0; o >>= 1) {
        #pragma unroll
        for (int r = 0; r < 4; ++r) {
            s[r]  += __shfl_xor(s[r],  o);
            s2[r] += __shfl_xor(s2[r], o);
        }
    }
    int wid = j >> 6, lane = j & 63;
    if (lane == 0) {
        #pragma unroll
        for (int r = 0; r < 4; ++r) { redS[r][wid] = s[r]; redS2[r][wid] = s2[r]; }
    }
    __syncthreads();
    if (j < 4) {
        int r = j;
        float ts  = redS[r][0]  + redS[r][1]  + redS[r][2]  + redS[r][3];
        float ts2 = redS2[r][0] + redS2[r][1] + redS2[r][2] + redS2[r][3];
        float mean = ts * (1.f / DD);
        float var = ts2 * (1.f / DD) - mean * mean;
        mu[r] = mean;
        ri[r] = rsqrtf(var + 1e-5f);
    }
    __syncthreads();
    float g = gam[j], be = bet[j];
    #pragma unroll
    for (int r = 0; r < 4; ++r) {
        float o = (val[r] - mu[r]) * ri[r] * g + be;
        x[(size_t)(r0 + r) * DD + j] = o;
        if (qp) xq[(size_t)(r0 + r) * DD + j] = o + qp[(size_t)(r0 + r) * DD + j];
    }
}

extern "C" void kernel_launch(void* const* d_in, const int* in_sizes, int n_in,
                              void* d_out, int out_size, void* d_ws, size_t ws_size,
                              hipStream_t stream) {
    const float* tgt       = (const float*)d_in[0];
    const float* query_pos = (const float*)d_in[1];
    const float* refpts    = (const float*)d_in[2];
    const float* feat0     = (const float*)d_in[3];
    const float* feat1     = (const float*)d_in[4];
    const float* feat2     = (const float*)d_in[5];
    const float* camR      = (const float*)d_in[6];
    const float* camT      = (const float*)d_in[7];
    const float* camK      = (const float*)d_in[8];
    const float* Wqkv      = (const float*)d_in[9];
    const float* bqkv      = (const float*)d_in[10];
    const float* Wo        = (const float*)d_in[11];
    const float* bo        = (const float*)d_in[12];
    const float* ln1_g     = (const float*)d_in[13];
    const float* ln1_b     = (const float*)d_in[14];
    const float* Wproj     = (const float*)d_in[15];
    const float* bproj     = (const float*)d_in[16];
    const float* pn_g      = (const float*)d_in[17];
    const float* pn_b      = (const float*)d_in[18];
    const float* W1        = (const float*)d_in[19];
    const float* b1        = (const float*)d_in[20];
    const float* W2        = (const float*)d_in[21];
    const float* b2        = (const float*)d_in[22];
    const float* ln2_g     = (const float*)d_in[23];
    const float* ln2_b     = (const float*)d_in[24];
    const float* pose_W0   = (const float*)d_in[25];
    const float* pose_b0   = (const float*)d_in[26];
    const float* pose_W1   = (const float*)d_in[27];
    const float* pose_b1   = (const float*)d_in[28];
    const float* pose_W2   = (const float*)d_in[29];
    const float* pose_b2   = (const float*)d_in[30];
    const float* cls_W     = (const float*)d_in[31];
    const float* cls_b     = (const float*)d_in[32];
    float* out = (float*)d_out;

    float* w = (float*)d_ws;
    size_t off = 0;
    auto alloc = [&](size_t n) { float* p = w + off; off += n; return p; };
    float* x      = alloc((size_t)BQ * DD);
    float* xq     = alloc((size_t)BQ * DD);
    float* Qp     = alloc((size_t)BB * HEADS * NQ * HD);
    float* Kp     = alloc((size_t)BB * HEADS * NQ * HD);
    float* Vp     = alloc((size_t)BB * HEADS * NQ * HD);
    float* attn_o = alloc((size_t)BQ * DD);
    float* fused  = alloc((size_t)BQ * DD);
    float* ffh    = alloc((size_t)BQ * FF);
    float* ctmp   = alloc((size_t)4 * BQ * DD);
    float* refb   = alloc((size_t)BQ * 3 + 64);
    size_t base_floats = off;
    size_t featT_floats = (size_t)BB * VV * DD * (64 * 64 + 32 * 32 + 16 * 16);
    bool useT = ws_size >= (base_floats + featT_floats) * sizeof(float);
    float *fT0 = nullptr, *fT1 = nullptr, *fT2 = nullptr;
    if (useT) {
        fT0 = alloc((size_t)BB * VV * 64 * 64 * DD);
        fT1 = alloc((size_t)BB * VV * 32 * 32 * DD);
        fT2 = alloc((size_t)BB * VV * 16 * 16 * DD);
    }

    // init x, xq, refb (168 blocks). Separate dispatch: layer-0 qkv reads xq.
    init_k<<<168, 256, 0, stream>>>(tgt, query_pos, refpts, x, xq, refb);

    for (int l = 0; l < NL; ++l) {
        // A: qkv (252) + [l==0: full feature transpose (5376)] / [l>0: pose head (168)]
        if (l == 0 && useT) {
            qkv_tr<<<252 + 5376, 256, 0, stream>>>(
                xq, x, Wqkv, bqkv, Qp, Kp, Vp,
                feat0, feat1, feat2, fT0, fT1, fT2);
        } else {
            qkv_pose<<<252 + (l > 0 ? 168 : 0), 256, 0, stream>>>(
                xq, x, Wqkv + (size_t)l * 3 * DD * DD, bqkv + (size_t)l * 3 * DD, Qp, Kp, Vp,
                pose_W0, pose_b0, pose_W1, pose_b1, pose_W2, pose_b2, cls_W, cls_b,
                refb, out + (size_t)(l - 1) * BQ * 4);
        }
        // B: fused attention, 16-row tiles (352 blocks, 39 KB LDS)
        attn16<<<352, 256, 0, stream>>>(Qp, Kp, Vp, attn_o);
        // D: oproj+res+LN1 (168, hides under sample) + sample (672)
        if (useT)
            oproj_sample<true><<<840, 256, 0, stream>>>(
                attn_o, Wo + (size_t)l * DD * DD, bo + (size_t)l * DD,
                ln1_g + (size_t)l * DD, ln1_b + (size_t)l * DD, x,
                fT0, fT1, fT2, refb, camR, camT, camK, fused);
        else
            oproj_sample<false><<<840, 256, 0, stream>>>(
                attn_o, Wo + (size_t)l * DD * DD, bo + (size_t)l * DD,
                ln1_g + (size_t)l * DD, ln1_b + (size_t)l * DD, x,
                feat0, feat1, feat2, refb, camR, camT, camK, fused);
        // E: proj-GEMM as tiled k-split (336 blocks, W read 21x not 168x) + ln_res.
        // Replaces the weight-row-per-thread gemm4_res_ln (serial load chain, ~16us).
        gemm_tile<0><<<dim3(21, 4, 4), 256, 0, stream>>>(
            fused, Wproj + (size_t)l * DD * DD, bproj + (size_t)l * DD, ctmp, DD, DD / 4, DD);
        ln_res<4><<<BQ / 4, 256, 0, stream>>>(
            x, ctmp, pn_g + (size_t)l * DD, pn_b + (size_t)l * DD, nullptr, nullptr);
        // FFN1 (relu)
        gemm_tile<1><<<dim3(21, 16, 1), 256, 0, stream>>>(
            x, W1 + (size_t)l * FF * DD, b1 + (size_t)l * FF, ffh, DD, DD, FF);
        // FFN2 k-split (336 blocks) + ln_res (168): occupancy beats fusion here (r2).
        gemm_tile<0><<<dim3(21, 4, 4), 256, 0, stream>>>(
            ffh, W2 + (size_t)l * DD * FF, b2 + (size_t)l * DD, ctmp, FF, FF / 4, DD);
        ln_res<4><<<BQ / 4, 256, 0, stream>>>(
            x, ctmp, ln2_g + (size_t)l * DD, ln2_b + (size_t)l * DD, query_pos, xq);
    }
    // tail: pose head of layer NL-1
    pose_only<<<BQ / 4, 256, 0, stream>>>(
        x, pose_W0, pose_b0, pose_W1, pose_b1, pose_W2, pose_b2, cls_W, cls_b,
        refb, out + (size_t)(NL - 1) * BQ * 4);
}